// Round 1
// baseline (33238.388 us; speedup 1.0000x reference)
//
#include <hip/hip_runtime.h>

#define BB 32
#define MEE 384
#define RRELS 128
#define NNODES 512
#define HSZ 500
#define DHEAD 125
#define NHEADS_ 4
#define HID 2000
#define NLAYER 2

// ======================= build nodes =======================
__global__ __launch_bounds__(256) void build_nodes_k(
    const float* __restrict__ ent_vec, const int* __restrict__ entity_num,
    const int* __restrict__ rels, const float* __restrict__ rel_embed,
    float* __restrict__ nodes)
{
    int b = blockIdx.x / NNODES;
    int n = blockIdx.x % NNODES;
    int e = entity_num[b];
    const float* src = nullptr;
    if (n < e)               src = ent_vec + ((size_t)b * MEE + n) * HSZ;
    else if (n < e + RRELS)  src = rel_embed + (size_t)rels[b * RRELS + (n - e)] * HSZ;
    float* dst = nodes + ((size_t)b * NNODES + n) * HSZ;
    if (src) { for (int d = threadIdx.x; d < HSZ; d += 256) dst[d] = src[d]; }
    else     { for (int d = threadIdx.x; d < HSZ; d += 256) dst[d] = 0.f; }
}

// ======================= generic fp32 GEMM: C = A@W + bias (opt PReLU) ===========
// A: [M,K] row-major, W: [K,N] row-major, C: [M,N]. M % 64 == 0.
#define BM 64
#define BN 64
#define BK 16
__global__ __launch_bounds__(256) void gemm_bias_k(
    const float* __restrict__ A, const float* __restrict__ W,
    const float* __restrict__ bias, float* __restrict__ C,
    int M, int N, int K, const float* __restrict__ prelu_a)
{
    __shared__ float As[BK][BM + 4];
    __shared__ float Bs[BK][BN + 4];
    int bm = blockIdx.y * BM;
    int bn = blockIdx.x * BN;
    int tid = threadIdx.x;
    int tr = tid >> 4;   // 0..15
    int tc = tid & 15;   // 0..15
    float acc[4][4] = {};

    for (int k0 = 0; k0 < K; k0 += BK) {
        // stage A tile (64 rows x 16 k), coalesced on K
        for (int i = tid; i < BM * BK; i += 256) {
            int m = i >> 4, kk = i & 15;
            int gk = k0 + kk;
            As[kk][m] = (gk < K) ? A[(size_t)(bm + m) * K + gk] : 0.f;
        }
        // stage B tile (16 k x 64 n), coalesced on N
        for (int i = tid; i < BK * BN; i += 256) {
            int kk = i >> 6, n = i & 63;
            int gk = k0 + kk, gn = bn + n;
            Bs[kk][n] = (gk < K && gn < N) ? W[(size_t)gk * N + gn] : 0.f;
        }
        __syncthreads();
#pragma unroll
        for (int kk = 0; kk < BK; ++kk) {
            float4 av = *(const float4*)&As[kk][tr * 4];
            float4 bv = *(const float4*)&Bs[kk][tc * 4];
            float a_[4] = {av.x, av.y, av.z, av.w};
            float b_[4] = {bv.x, bv.y, bv.z, bv.w};
#pragma unroll
            for (int i = 0; i < 4; ++i)
#pragma unroll
                for (int j = 0; j < 4; ++j)
                    acc[i][j] += a_[i] * b_[j];
        }
        __syncthreads();
    }
#pragma unroll
    for (int i = 0; i < 4; ++i) {
        int gm = bm + tr * 4 + i;
#pragma unroll
        for (int j = 0; j < 4; ++j) {
            int gn = bn + tc * 4 + j;
            if (gn < N) {
                float v = acc[i][j] + bias[gn];
                if (prelu_a) { float al = prelu_a[gn]; v = v > 0.f ? v : al * v; }
                C[(size_t)gm * N + gn] = v;
            }
        }
    }
}

// ======================= fused masked attention =======================
// grid: b * 4 heads * 32 q-tiles (of 16 rows). block 256.
__global__ __launch_bounds__(256) void attn_k(
    const float* __restrict__ Q, const float* __restrict__ K,
    const float* __restrict__ V, const int* __restrict__ adj,
    float* __restrict__ ctx)
{
    const int NQT = NNODES / 16;  // 32
    int blk = blockIdx.x;
    int qt = blk % NQT;
    int h  = (blk / NQT) % NHEADS_;
    int b  = blk / (NQT * NHEADS_);
    int q0 = qt * 16;
    int t  = threadIdx.x;
    int qr = t >> 4;   // 0..15 : q row within tile
    int lc = t & 15;   // 0..15

    __shared__ float Qs[16][132];
    __shared__ float Ks[64][132];
    __shared__ float S[16][NNODES];

    const float scale = 0.08944271909999159f;  // 1/sqrt(125)

    // stage Q tile (zero-pad dims 125..127)
    {
        const float* qbase = Q + ((size_t)b * NNODES + q0) * HSZ + h * DHEAD;
        for (int i = t; i < 16 * 128; i += 256) {
            int r = i >> 7, d = i & 127;
            Qs[r][d] = (d < DHEAD) ? qbase[(size_t)r * HSZ + d] : 0.f;
        }
    }
    __syncthreads();

    // ---- phase 1: S = Q K^T ----
    for (int k0 = 0; k0 < NNODES; k0 += 64) {
        __syncthreads();  // protect Ks from previous iter readers
        const float* kbase = K + ((size_t)b * NNODES + k0) * HSZ + h * DHEAD;
        for (int i = t; i < 64 * 128; i += 256) {
            int r = i >> 7, d = i & 127;
            Ks[r][d] = (d < DHEAD) ? kbase[(size_t)r * HSZ + d] : 0.f;
        }
        __syncthreads();
        float acc4[4] = {0, 0, 0, 0};
#pragma unroll 8
        for (int d4 = 0; d4 < 32; ++d4) {
            float4 qv = *(const float4*)&Qs[qr][d4 * 4];
#pragma unroll
            for (int j = 0; j < 4; ++j) {
                float4 kv = *(const float4*)&Ks[lc + 16 * j][d4 * 4];
                acc4[j] += qv.x * kv.x + qv.y * kv.y + qv.z * kv.z + qv.w * kv.w;
            }
        }
#pragma unroll
        for (int j = 0; j < 4; ++j) S[qr][k0 + lc + 16 * j] = acc4[j];
    }
    __syncthreads();

    // ---- phase 2: masked softmax over rows ----
    {
        int gq = q0 + qr;
        const int* arow = adj + ((size_t)b * NNODES + gq) * NNODES;
        float vals[32];
        float mx = -3e38f;
#pragma unroll
        for (int j = 0; j < 32; ++j) {
            int c = lc + 16 * j;
            float s = S[qr][c];
            s = (arow[c] != 0) ? s * scale : -1e9f;
            vals[j] = s;
            mx = fmaxf(mx, s);
        }
        for (int o = 1; o < 16; o <<= 1) mx = fmaxf(mx, __shfl_xor(mx, o));
        float sum = 0.f;
#pragma unroll
        for (int j = 0; j < 32; ++j) { vals[j] = __expf(vals[j] - mx); sum += vals[j]; }
        for (int o = 1; o < 16; o <<= 1) sum += __shfl_xor(sum, o);
        float inv = 1.0f / sum;
#pragma unroll
        for (int j = 0; j < 32; ++j) S[qr][lc + 16 * j] = vals[j] * inv;
    }
    __syncthreads();

    // ---- phase 3: ctx = P V ----
    float acc[8] = {};
    for (int k0 = 0; k0 < NNODES; k0 += 64) {
        __syncthreads();  // protect Ks overwrite
        const float* vbase = V + ((size_t)b * NNODES + k0) * HSZ + h * DHEAD;
        for (int i = t; i < 64 * 128; i += 256) {
            int r = i >> 7, d = i & 127;
            Ks[r][d] = (d < DHEAD) ? vbase[(size_t)r * HSZ + d] : 0.f;
        }
        __syncthreads();
        for (int kk = 0; kk < 64; ++kk) {
            float p = S[qr][k0 + kk];
            float4 va = *(const float4*)&Ks[kk][lc * 4];
            float4 vb = *(const float4*)&Ks[kk][64 + lc * 4];
            acc[0] += p * va.x; acc[1] += p * va.y; acc[2] += p * va.z; acc[3] += p * va.w;
            acc[4] += p * vb.x; acc[5] += p * vb.y; acc[6] += p * vb.z; acc[7] += p * vb.w;
        }
    }
    {
        int gq = q0 + qr;
        float* cb = ctx + ((size_t)b * NNODES + gq) * HSZ + h * DHEAD;
#pragma unroll
        for (int i = 0; i < 4; ++i) cb[lc * 4 + i] = acc[i];           // d < 64
#pragma unroll
        for (int i = 0; i < 4; ++i) {
            int d = 64 + lc * 4 + i;
            if (d < DHEAD) cb[d] = acc[4 + i];
        }
    }
}

// ======================= layernorm (optional residual) =======================
__global__ __launch_bounds__(256) void ln_k(
    const float* __restrict__ x, const float* __restrict__ res,
    const float* __restrict__ g, const float* __restrict__ bta,
    float* __restrict__ out)
{
    size_t row = blockIdx.x;
    const float* xr = x + row * HSZ;
    const float* rr = res ? res + row * HSZ : nullptr;
    int t = threadIdx.x;
    float v[2];
    float s = 0.f, s2 = 0.f;
#pragma unroll
    for (int i = 0; i < 2; ++i) {
        int d = t + i * 256;
        float val = 0.f;
        if (d < HSZ) { val = xr[d]; if (rr) val += rr[d]; }
        v[i] = val; s += val; s2 += val * val;
    }
    __shared__ float red[8];
    int wave = t >> 6, lane = t & 63;
    for (int o = 1; o < 64; o <<= 1) { s += __shfl_xor(s, o); s2 += __shfl_xor(s2, o); }
    if (lane == 0) { red[wave] = s; red[4 + wave] = s2; }
    __syncthreads();
    s  = red[0] + red[1] + red[2] + red[3];
    s2 = red[4] + red[5] + red[6] + red[7];
    float mean = s / HSZ;
    float var  = s2 / HSZ - mean * mean;
    float rstd = rsqrtf(var + 1e-5f);
    float* orow = out + row * HSZ;
#pragma unroll
    for (int i = 0; i < 2; ++i) {
        int d = t + i * 256;
        if (d < HSZ) orow[d] = (v[i] - mean) * rstd * g[d] + bta[d];
    }
}

// ======================= finalize: glob, node_emb, mask =======================
__global__ __launch_bounds__(256) void finalize_k(
    const float* __restrict__ nodes, const int* __restrict__ entity_num,
    float* __restrict__ out)
{
    int b = blockIdx.x / NNODES;
    int n = blockIdx.x % NNODES;
    int e = entity_num[b];
    int size = e + RRELS;
    const float* src = nodes + ((size_t)b * NNODES + n) * HSZ;
    float* ne = out + (size_t)BB * HSZ + ((size_t)b * NNODES + n) * HSZ;
    bool valid = n < size;
    for (int d = threadIdx.x; d < HSZ; d += 256) ne[d] = valid ? src[d] : 0.f;
    if (n == e) {
        float* gl = out + (size_t)b * HSZ;
        for (int d = threadIdx.x; d < HSZ; d += 256) gl[d] = src[d];
    }
    if (threadIdx.x == 0) {
        out[(size_t)BB * HSZ + (size_t)BB * NNODES * HSZ + (size_t)b * NNODES + n] =
            (n <= size) ? 1.f : 0.f;
    }
}

// ======================= host =======================
extern "C" void kernel_launch(void* const* d_in, const int* in_sizes, int n_in,
                              void* d_out, int out_size, void* d_ws, size_t ws_size,
                              hipStream_t stream)
{
    const float* ent_vec    = (const float*)d_in[0];
    const int*   entity_num = (const int*)d_in[1];
    const int*   rels       = (const int*)d_in[2];
    const int*   adj        = (const int*)d_in[3];
    const float* rel_embed  = (const float*)d_in[4];
    const float* Wq = (const float*)d_in[5],  *bq = (const float*)d_in[6];
    const float* Wk = (const float*)d_in[7],  *bk = (const float*)d_in[8];
    const float* Wv = (const float*)d_in[9],  *bv = (const float*)d_in[10];
    const float* Wo = (const float*)d_in[11], *bo = (const float*)d_in[12];
    const float* W1 = (const float*)d_in[13], *b1 = (const float*)d_in[14];
    const float* W2 = (const float*)d_in[15], *b2 = (const float*)d_in[16];
    const float* ln1g = (const float*)d_in[17], *ln1b = (const float*)d_in[18];
    const float* ln2g = (const float*)d_in[19], *ln2b = (const float*)d_in[20];
    const float* pa = (const float*)d_in[21];

    const int M = BB * NNODES;               // 16384
    const size_t BUF = (size_t)M * HSZ;      // 8,192,000 floats
    float* w = (float*)d_ws;
    float* bufs[4] = {w, w + BUF, w + 2 * BUF, w + 3 * BUF};

    build_nodes_k<<<BB * NNODES, 256, 0, stream>>>(ent_vec, entity_num, rels, rel_embed, bufs[0]);

    int xi = 0;
    for (int l = 0; l < NLAYER; ++l) {
        int i1 = (xi + 1) & 3, i2 = (xi + 2) & 3, i3 = (xi + 3) & 3;
        float* X = bufs[xi];
        float* q = bufs[i1];
        float* k = bufs[i2];
        float* v = bufs[i3];

        const float* Wq_l = Wq + (size_t)l * HSZ * HSZ; const float* bq_l = bq + (size_t)l * HSZ;
        const float* Wk_l = Wk + (size_t)l * HSZ * HSZ; const float* bk_l = bk + (size_t)l * HSZ;
        const float* Wv_l = Wv + (size_t)l * HSZ * HSZ; const float* bv_l = bv + (size_t)l * HSZ;
        const float* Wo_l = Wo + (size_t)l * HSZ * HSZ; const float* bo_l = bo + (size_t)l * HSZ;
        const float* W1_l = W1 + (size_t)l * HSZ * HID; const float* b1_l = b1 + (size_t)l * HID;
        const float* W2_l = W2 + (size_t)l * HID * HSZ; const float* b2_l = b2 + (size_t)l * HSZ;
        const float* pa_l = pa + (size_t)l * HID;

        dim3 g500((HSZ + BN - 1) / BN, M / BM);  // (8, 256)
        gemm_bias_k<<<g500, 256, 0, stream>>>(X, Wq_l, bq_l, q, M, HSZ, HSZ, nullptr);
        gemm_bias_k<<<g500, 256, 0, stream>>>(X, Wk_l, bk_l, k, M, HSZ, HSZ, nullptr);
        gemm_bias_k<<<g500, 256, 0, stream>>>(X, Wv_l, bv_l, v, M, HSZ, HSZ, nullptr);

        attn_k<<<BB * NHEADS_ * (NNODES / 16), 256, 0, stream>>>(q, k, v, adj, X); // ctx -> X

        gemm_bias_k<<<g500, 256, 0, stream>>>(X, Wo_l, bo_l, q, M, HSZ, HSZ, nullptr); // o -> q
        ln_k<<<M, 256, 0, stream>>>(q, nullptr, ln1g + (size_t)l * HSZ, ln1b + (size_t)l * HSZ, k); // t -> k

        // FFN in 4 chunks of 4096 rows; h1 reuses v (4096*2000 == BUF)
        const int CH = 4096;
        for (int c = 0; c < 4; ++c) {
            const float* tch = k + (size_t)c * CH * HSZ;
            float* fch = X + (size_t)c * CH * HSZ;  // f -> X (ctx dead)
            dim3 gh((HID + BN - 1) / BN, CH / BM);  // (32, 64)
            gemm_bias_k<<<gh, 256, 0, stream>>>(tch, W1_l, b1_l, v, CH, HID, HSZ, pa_l);
            dim3 gf((HSZ + BN - 1) / BN, CH / BM);  // (8, 64)
            gemm_bias_k<<<gf, 256, 0, stream>>>(v, W2_l, b2_l, fch, CH, HSZ, HID, nullptr);
        }
        ln_k<<<M, 256, 0, stream>>>(X, k, ln2g + (size_t)l * HSZ, ln2b + (size_t)l * HSZ, q); // newX -> q
        xi = i1;
    }

    finalize_k<<<BB * NNODES, 256, 0, stream>>>(bufs[xi], entity_num, (float*)d_out);
}

// Round 2
// 7056.934 us; speedup vs baseline: 4.7100x; 4.7100x over previous
//
#include <hip/hip_runtime.h>

#define BB 32
#define MEE 384
#define RRELS 128
#define NNODES 512
#define HSZ 500
#define DHEAD 125
#define NHEADS_ 4
#define HID 2000
#define NLAYER 2

// ======================= build nodes =======================
__global__ __launch_bounds__(256) void build_nodes_k(
    const float* __restrict__ ent_vec, const int* __restrict__ entity_num,
    const int* __restrict__ rels, const float* __restrict__ rel_embed,
    float* __restrict__ nodes)
{
    int b = blockIdx.x / NNODES;
    int n = blockIdx.x % NNODES;
    int e = entity_num[b];
    const float* src = nullptr;
    if (n < e)               src = ent_vec + ((size_t)b * MEE + n) * HSZ;
    else if (n < e + RRELS)  src = rel_embed + (size_t)rels[b * RRELS + (n - e)] * HSZ;
    float* dst = nodes + ((size_t)b * NNODES + n) * HSZ;
    if (src) { for (int d = threadIdx.x; d < HSZ; d += 256) dst[d] = src[d]; }
    else     { for (int d = threadIdx.x; d < HSZ; d += 256) dst[d] = 0.f; }
}

// ======================= adjacency -> bitmask =======================
// bits[b][n][w] : bit i = (adj[b][n][w*32+i] != 0). One wave handles 64 ints.
__global__ __launch_bounds__(256) void adj_bits_k(
    const int* __restrict__ adj, unsigned int* __restrict__ bits)
{
    int gw = (blockIdx.x * 256 + threadIdx.x) >> 6;   // global wave id
    int lane = threadIdx.x & 63;
    int v = adj[(size_t)gw * 64 + lane];
    unsigned long long mk = __ballot(v != 0);
    if (lane == 0)  bits[gw * 2]     = (unsigned int)mk;
    if (lane == 32) bits[gw * 2 + 1] = (unsigned int)(mk >> 32);
}

// ======================= generic fp32 GEMM: C = A@W + bias (opt PReLU) ===========
#define BM 64
#define BN 64
#define BK 16
__global__ __launch_bounds__(256) void gemm_bias_k(
    const float* __restrict__ A, const float* __restrict__ W,
    const float* __restrict__ bias, float* __restrict__ C,
    int M, int N, int K, const float* __restrict__ prelu_a)
{
    __shared__ float As[BK][BM + 4];
    __shared__ float Bs[BK][BN + 4];
    int bm = blockIdx.y * BM;
    int bn = blockIdx.x * BN;
    int tid = threadIdx.x;
    int tr = tid >> 4;
    int tc = tid & 15;
    float acc[4][4] = {};

    for (int k0 = 0; k0 < K; k0 += BK) {
        for (int i = tid; i < BM * BK; i += 256) {
            int m = i >> 4, kk = i & 15;
            int gk = k0 + kk;
            As[kk][m] = (gk < K) ? A[(size_t)(bm + m) * K + gk] : 0.f;
        }
        for (int i = tid; i < BK * BN; i += 256) {
            int kk = i >> 6, n = i & 63;
            int gk = k0 + kk, gn = bn + n;
            Bs[kk][n] = (gk < K && gn < N) ? W[(size_t)gk * N + gn] : 0.f;
        }
        __syncthreads();
#pragma unroll
        for (int kk = 0; kk < BK; ++kk) {
            float4 av = *(const float4*)&As[kk][tr * 4];
            float4 bv = *(const float4*)&Bs[kk][tc * 4];
            float a_[4] = {av.x, av.y, av.z, av.w};
            float b_[4] = {bv.x, bv.y, bv.z, bv.w};
#pragma unroll
            for (int i = 0; i < 4; ++i)
#pragma unroll
                for (int j = 0; j < 4; ++j)
                    acc[i][j] += a_[i] * b_[j];
        }
        __syncthreads();
    }
#pragma unroll
    for (int i = 0; i < 4; ++i) {
        int gm = bm + tr * 4 + i;
#pragma unroll
        for (int j = 0; j < 4; ++j) {
            int gn = bn + tc * 4 + j;
            if (gn < N) {
                float v = acc[i][j] + bias[gn];
                if (prelu_a) { float al = prelu_a[gn]; v = v > 0.f ? v : al * v; }
                C[(size_t)gm * N + gn] = v;
            }
        }
    }
}

// ======================= flash attention (masked, online softmax) ==============
// grid: b * 4 heads * 8 q-tiles (of 64 rows). block 256 = 64 rows x 4 subs.
// thread (qr = t>>2, sub = t&3): owns dims [sub*32, sub*32+32) of its q-row.
#define KT 32
__global__ __launch_bounds__(256) void attn_k(
    const float* __restrict__ Q, const float* __restrict__ K,
    const float* __restrict__ V, const unsigned int* __restrict__ abits,
    float* __restrict__ ctx)
{
    int blk = blockIdx.x;
    int qt = blk & 7;
    int h  = (blk >> 3) & 3;
    int b  = blk >> 5;
    int t  = threadIdx.x;
    int qr = t >> 2, sub = t & 3;
    int gq = qt * 64 + qr;

    __shared__ float Kt[KT][128];
    __shared__ float Vt[KT][128];

    const float scale = 0.08944271909999159f;  // 1/sqrt(125)
    const size_t rowQ = ((size_t)b * NNODES + gq) * HSZ + (size_t)h * DHEAD;

    float qreg[32];
#pragma unroll
    for (int i4 = 0; i4 < 8; ++i4) {
        int d = sub * 32 + i4 * 4;
        if (d + 3 < DHEAD) {
            float4 qv = *(const float4*)&Q[rowQ + d];
            qreg[i4 * 4]     = qv.x; qreg[i4 * 4 + 1] = qv.y;
            qreg[i4 * 4 + 2] = qv.z; qreg[i4 * 4 + 3] = qv.w;
        } else {
#pragma unroll
            for (int c = 0; c < 4; ++c)
                qreg[i4 * 4 + c] = (d + c < DHEAD) ? Q[rowQ + d + c] : 0.f;
        }
    }

    float acc[32] = {};
    float m = -3e38f, l = 0.f;
    const unsigned int* abrow = abits + ((size_t)b * NNODES + gq) * 16;

    for (int kt = 0; kt < NNODES / KT; ++kt) {
        __syncthreads();   // previous tile fully consumed
        {
            const float* kb = K + ((size_t)b * NNODES + kt * KT) * HSZ + h * DHEAD;
            const float* vb = V + ((size_t)b * NNODES + kt * KT) * HSZ + h * DHEAD;
            for (int i = t; i < KT * 32; i += 256) {  // 32 float4 per row
                int r = i >> 5, c4 = (i & 31) * 4;
                float4 kv, vv;
                if (c4 + 3 < DHEAD) {
                    kv = *(const float4*)&kb[(size_t)r * HSZ + c4];
                    vv = *(const float4*)&vb[(size_t)r * HSZ + c4];
                } else {
                    float tk[4], tv[4];
#pragma unroll
                    for (int c = 0; c < 4; ++c) {
                        bool ok = (c4 + c < DHEAD);
                        tk[c] = ok ? kb[(size_t)r * HSZ + c4 + c] : 0.f;
                        tv[c] = ok ? vb[(size_t)r * HSZ + c4 + c] : 0.f;
                    }
                    kv = make_float4(tk[0], tk[1], tk[2], tk[3]);
                    vv = make_float4(tv[0], tv[1], tv[2], tv[3]);
                }
                *(float4*)&Kt[r][c4] = kv;
                *(float4*)&Vt[r][c4] = vv;
            }
        }
        __syncthreads();

        unsigned int word = abrow[kt];

        for (int j0 = 0; j0 < KT; j0 += 8) {
            float s[8];
#pragma unroll
            for (int jj = 0; jj < 8; ++jj) {
                int j = j0 + jj;
                float a0 = 0.f;
#pragma unroll
                for (int i4 = 0; i4 < 8; ++i4) {
                    float4 kv = *(const float4*)&Kt[j][sub * 32 + i4 * 4];
                    a0 += qreg[i4 * 4] * kv.x + qreg[i4 * 4 + 1] * kv.y
                        + qreg[i4 * 4 + 2] * kv.z + qreg[i4 * 4 + 3] * kv.w;
                }
                s[jj] = a0;
            }
#pragma unroll
            for (int jj = 0; jj < 8; ++jj) {
                s[jj] += __shfl_xor(s[jj], 1);
                s[jj] += __shfl_xor(s[jj], 2);
            }
            float mnew = m;
#pragma unroll
            for (int jj = 0; jj < 8; ++jj) {
                bool on = (word >> (j0 + jj)) & 1u;
                s[jj] = on ? s[jj] * scale : -1e9f;
                mnew = fmaxf(mnew, s[jj]);
            }
            float f = __expf(m - mnew);
            m = mnew;
            l *= f;
#pragma unroll
            for (int i = 0; i < 32; ++i) acc[i] *= f;
#pragma unroll
            for (int jj = 0; jj < 8; ++jj) {
                float p = __expf(s[jj] - m);
                l += p;
                int j = j0 + jj;
#pragma unroll
                for (int i4 = 0; i4 < 8; ++i4) {
                    float4 vv = *(const float4*)&Vt[j][sub * 32 + i4 * 4];
                    acc[i4 * 4]     += p * vv.x;
                    acc[i4 * 4 + 1] += p * vv.y;
                    acc[i4 * 4 + 2] += p * vv.z;
                    acc[i4 * 4 + 3] += p * vv.w;
                }
            }
        }
    }

    float inv = 1.f / l;
    float* cb = ctx + rowQ;
#pragma unroll
    for (int i = 0; i < 32; ++i) {
        int d = sub * 32 + i;
        if (d < DHEAD) cb[d] = acc[i] * inv;
    }
}

// ======================= layernorm (optional residual) =======================
__global__ __launch_bounds__(256) void ln_k(
    const float* __restrict__ x, const float* __restrict__ res,
    const float* __restrict__ g, const float* __restrict__ bta,
    float* __restrict__ out)
{
    size_t row = blockIdx.x;
    const float* xr = x + row * HSZ;
    const float* rr = res ? res + row * HSZ : nullptr;
    int t = threadIdx.x;
    float v[2];
    float s = 0.f, s2 = 0.f;
#pragma unroll
    for (int i = 0; i < 2; ++i) {
        int d = t + i * 256;
        float val = 0.f;
        if (d < HSZ) { val = xr[d]; if (rr) val += rr[d]; }
        v[i] = val; s += val; s2 += val * val;
    }
    __shared__ float red[8];
    int wave = t >> 6, lane = t & 63;
    for (int o = 1; o < 64; o <<= 1) { s += __shfl_xor(s, o); s2 += __shfl_xor(s2, o); }
    if (lane == 0) { red[wave] = s; red[4 + wave] = s2; }
    __syncthreads();
    s  = red[0] + red[1] + red[2] + red[3];
    s2 = red[4] + red[5] + red[6] + red[7];
    float mean = s / HSZ;
    float var  = s2 / HSZ - mean * mean;
    float rstd = rsqrtf(var + 1e-5f);
    float* orow = out + row * HSZ;
#pragma unroll
    for (int i = 0; i < 2; ++i) {
        int d = t + i * 256;
        if (d < HSZ) orow[d] = (v[i] - mean) * rstd * g[d] + bta[d];
    }
}

// ======================= finalize: glob, node_emb, mask =======================
__global__ __launch_bounds__(256) void finalize_k(
    const float* __restrict__ nodes, const int* __restrict__ entity_num,
    float* __restrict__ out)
{
    int b = blockIdx.x / NNODES;
    int n = blockIdx.x % NNODES;
    int e = entity_num[b];
    int size = e + RRELS;
    const float* src = nodes + ((size_t)b * NNODES + n) * HSZ;
    float* ne = out + (size_t)BB * HSZ + ((size_t)b * NNODES + n) * HSZ;
    bool valid = n < size;
    for (int d = threadIdx.x; d < HSZ; d += 256) ne[d] = valid ? src[d] : 0.f;
    if (n == e) {
        float* gl = out + (size_t)b * HSZ;
        for (int d = threadIdx.x; d < HSZ; d += 256) gl[d] = src[d];
    }
    if (threadIdx.x == 0) {
        out[(size_t)BB * HSZ + (size_t)BB * NNODES * HSZ + (size_t)b * NNODES + n] =
            (n <= size) ? 1.f : 0.f;
    }
}

// ======================= host =======================
extern "C" void kernel_launch(void* const* d_in, const int* in_sizes, int n_in,
                              void* d_out, int out_size, void* d_ws, size_t ws_size,
                              hipStream_t stream)
{
    const float* ent_vec    = (const float*)d_in[0];
    const int*   entity_num = (const int*)d_in[1];
    const int*   rels       = (const int*)d_in[2];
    const int*   adj        = (const int*)d_in[3];
    const float* rel_embed  = (const float*)d_in[4];
    const float* Wq = (const float*)d_in[5],  *bq = (const float*)d_in[6];
    const float* Wk = (const float*)d_in[7],  *bk = (const float*)d_in[8];
    const float* Wv = (const float*)d_in[9],  *bv = (const float*)d_in[10];
    const float* Wo = (const float*)d_in[11], *bo = (const float*)d_in[12];
    const float* W1 = (const float*)d_in[13], *b1 = (const float*)d_in[14];
    const float* W2 = (const float*)d_in[15], *b2 = (const float*)d_in[16];
    const float* ln1g = (const float*)d_in[17], *ln1b = (const float*)d_in[18];
    const float* ln2g = (const float*)d_in[19], *ln2b = (const float*)d_in[20];
    const float* pa = (const float*)d_in[21];

    const int M = BB * NNODES;               // 16384
    const size_t BUF = (size_t)M * HSZ;      // 8,192,000 floats
    float* w = (float*)d_ws;
    float* bufs[4] = {w, w + BUF, w + 2 * BUF, w + 3 * BUF};

    // adjacency bitmask lives in d_out (finalize_k later overwrites ALL of d_out)
    unsigned int* abits = (unsigned int*)d_out;  // 262144 words = 1 MB

    build_nodes_k<<<BB * NNODES, 256, 0, stream>>>(ent_vec, entity_num, rels, rel_embed, bufs[0]);
    adj_bits_k<<<(BB * NNODES * NNODES) / 64 / 4, 256, 0, stream>>>(adj, abits);

    int xi = 0;
    for (int l = 0; l < NLAYER; ++l) {
        int i1 = (xi + 1) & 3, i2 = (xi + 2) & 3, i3 = (xi + 3) & 3;
        float* X = bufs[xi];
        float* q = bufs[i1];
        float* k = bufs[i2];
        float* v = bufs[i3];

        const float* Wq_l = Wq + (size_t)l * HSZ * HSZ; const float* bq_l = bq + (size_t)l * HSZ;
        const float* Wk_l = Wk + (size_t)l * HSZ * HSZ; const float* bk_l = bk + (size_t)l * HSZ;
        const float* Wv_l = Wv + (size_t)l * HSZ * HSZ; const float* bv_l = bv + (size_t)l * HSZ;
        const float* Wo_l = Wo + (size_t)l * HSZ * HSZ; const float* bo_l = bo + (size_t)l * HSZ;
        const float* W1_l = W1 + (size_t)l * HSZ * HID; const float* b1_l = b1 + (size_t)l * HID;
        const float* W2_l = W2 + (size_t)l * HID * HSZ; const float* b2_l = b2 + (size_t)l * HSZ;
        const float* pa_l = pa + (size_t)l * HID;

        dim3 g500((HSZ + BN - 1) / BN, M / BM);  // (8, 256)
        gemm_bias_k<<<g500, 256, 0, stream>>>(X, Wq_l, bq_l, q, M, HSZ, HSZ, nullptr);
        gemm_bias_k<<<g500, 256, 0, stream>>>(X, Wk_l, bk_l, k, M, HSZ, HSZ, nullptr);
        gemm_bias_k<<<g500, 256, 0, stream>>>(X, Wv_l, bv_l, v, M, HSZ, HSZ, nullptr);

        attn_k<<<BB * NHEADS_ * (NNODES / 64), 256, 0, stream>>>(q, k, v, abits, X); // ctx -> X

        gemm_bias_k<<<g500, 256, 0, stream>>>(X, Wo_l, bo_l, q, M, HSZ, HSZ, nullptr); // o -> q
        ln_k<<<M, 256, 0, stream>>>(q, nullptr, ln1g + (size_t)l * HSZ, ln1b + (size_t)l * HSZ, k); // t -> k

        const int CH = 4096;
        for (int c = 0; c < 4; ++c) {
            const float* tch = k + (size_t)c * CH * HSZ;
            float* fch = X + (size_t)c * CH * HSZ;  // f -> X (ctx dead)
            dim3 gh((HID + BN - 1) / BN, CH / BM);  // (32, 64)
            gemm_bias_k<<<gh, 256, 0, stream>>>(tch, W1_l, b1_l, v, CH, HID, HSZ, pa_l);
            dim3 gf((HSZ + BN - 1) / BN, CH / BM);  // (8, 64)
            gemm_bias_k<<<gf, 256, 0, stream>>>(v, W2_l, b2_l, fch, CH, HSZ, HID, nullptr);
        }
        ln_k<<<M, 256, 0, stream>>>(X, k, ln2g + (size_t)l * HSZ, ln2b + (size_t)l * HSZ, q); // newX -> q
        xi = i1;
    }

    finalize_k<<<BB * NNODES, 256, 0, stream>>>(bufs[xi], entity_num, (float*)d_out);
}

// Round 3
// 1805.611 us; speedup vs baseline: 18.4084x; 3.9083x over previous
//
#include <hip/hip_runtime.h>

#define BB 32
#define MEE 384
#define RRELS 128
#define NNODES 512
#define HSZ 500
#define DHEAD 125
#define NHEADS_ 4
#define HID 2000
#define NLAYER 2

#define KP 512      // padded HSZ
#define HIDP 2048   // padded HID

typedef unsigned short ushort_t;
typedef __attribute__((ext_vector_type(8))) short bf16x8;
typedef __attribute__((ext_vector_type(4))) float f32x4;

static __device__ __forceinline__ unsigned short f2bf(float x) {
    unsigned u = __float_as_uint(x);
    u = u + 0x7fff + ((u >> 16) & 1);   // round-to-nearest-even
    return (unsigned short)(u >> 16);
}

static __device__ __forceinline__ void gload_lds16(const ushort_t* g, ushort_t* l) {
    __builtin_amdgcn_global_load_lds(
        (const __attribute__((address_space(1))) void*)g,
        (__attribute__((address_space(3))) void*)l, 16, 0, 0);
}

// ======================= build nodes (f32 + bf16-padded) =======================
__global__ __launch_bounds__(256) void build_nodes_k(
    const float* __restrict__ ent_vec, const int* __restrict__ entity_num,
    const int* __restrict__ rels, const float* __restrict__ rel_embed,
    float* __restrict__ nodes, ushort_t* __restrict__ xb)
{
    int b = blockIdx.x / NNODES;
    int n = blockIdx.x % NNODES;
    int e = entity_num[b];
    const float* src = nullptr;
    if (n < e)               src = ent_vec + ((size_t)b * MEE + n) * HSZ;
    else if (n < e + RRELS)  src = rel_embed + (size_t)rels[b * RRELS + (n - e)] * HSZ;
    float* dst = nodes + ((size_t)b * NNODES + n) * HSZ;
    ushort_t* xd = xb + ((size_t)b * NNODES + n) * KP;
    for (int d = threadIdx.x; d < KP; d += 256) {
        float v = (src && d < HSZ) ? src[d] : 0.f;
        if (d < HSZ) dst[d] = v;
        xd[d] = (d < HSZ) ? f2bf(v) : 0;
    }
}

// ======================= adjacency -> bitmask =======================
__global__ __launch_bounds__(256) void adj_bits_k(
    const int* __restrict__ adj, unsigned int* __restrict__ bits)
{
    int gw = (blockIdx.x * 256 + threadIdx.x) >> 6;
    int lane = threadIdx.x & 63;
    int v = adj[(size_t)gw * 64 + lane];
    unsigned long long mk = __ballot(v != 0);
    if (lane == 0)  bits[gw * 2]     = (unsigned int)mk;
    if (lane == 32) bits[gw * 2 + 1] = (unsigned int)(mk >> 32);
}

// ======================= weight convert: W[K][N] f32 -> Wt[Np][Kp] bf16 =========
__global__ __launch_bounds__(256) void wcvt_k(
    const float* __restrict__ W, ushort_t* __restrict__ out,
    int Kreal, int Nreal, int Kp, int Np)
{
    int idx = blockIdx.x * 256 + threadIdx.x;
    if (idx >= Kp * Np) return;
    int n = idx / Kp, k = idx - n * Kp;
    float v = (k < Kreal && n < Nreal) ? W[(size_t)k * Nreal + n] : 0.f;
    out[idx] = (k < Kreal && n < Nreal) ? f2bf(v) : 0;
}

// ======================= bf16 MFMA GEMM (m97-style 128x128, BK=32) ==============
// A: [M, Kp] bf16 row-major. Bt: [Np, Kp] bf16 (i.e. W^T). Outputs:
//   outF (f32 [M, Nreal]) and/or outB (bf16 [M, Np], zero-padded cols).
__global__ __launch_bounds__(256, 2) void gemm_mfma_k(
    const ushort_t* __restrict__ A, const ushort_t* __restrict__ Bt,
    const float* __restrict__ bias,
    float* __restrict__ outF, ushort_t* __restrict__ outB,
    int M, int Np, int Kp, int Nreal,
    const float* __restrict__ prelu)
{
    __shared__ ushort_t Al[128 * 32];
    __shared__ ushort_t Bl[128 * 32];
    const int bm = blockIdx.y * 128;
    const int bn = blockIdx.x * 128;
    const int tid = threadIdx.x;
    const int wid = tid >> 6, lane = tid & 63;
    const int wr = wid >> 1, wc = wid & 1;   // 2x2 wave grid, 64x64 per wave
    const int lr = lane & 15, lk = lane >> 4;

    f32x4 acc[4][4];
#pragma unroll
    for (int i = 0; i < 4; ++i)
#pragma unroll
        for (int j = 0; j < 4; ++j)
#pragma unroll
            for (int r = 0; r < 4; ++r) acc[i][j][r] = 0.f;

    // staging map: issue h covers LDS rows [h*64, h*64+64); thread -> row, kseg
    const int srow = tid >> 2;            // 0..63
    const int skseg = (tid & 3) * 8;
    const ushort_t* Ag0 = A + (size_t)(bm + srow) * Kp + skseg;
    const ushort_t* Ag1 = A + (size_t)(bm + 64 + srow) * Kp + skseg;
    const ushort_t* Bg0 = Bt + (size_t)(bn + srow) * Kp + skseg;
    const ushort_t* Bg1 = Bt + (size_t)(bn + 64 + srow) * Kp + skseg;
    ushort_t* Al0 = &Al[wid * 512];
    ushort_t* Al1 = &Al[2048 + wid * 512];
    ushort_t* Bl0 = &Bl[wid * 512];
    ushort_t* Bl1 = &Bl[2048 + wid * 512];

    for (int k0 = 0; k0 < Kp; k0 += 32) {
        __syncthreads();
        gload_lds16(Ag0 + k0, Al0);
        gload_lds16(Ag1 + k0, Al1);
        gload_lds16(Bg0 + k0, Bl0);
        gload_lds16(Bg1 + k0, Bl1);
        __syncthreads();

        bf16x8 af[4], bfr[4];
#pragma unroll
        for (int mi = 0; mi < 4; ++mi)
            af[mi] = *(const bf16x8*)&Al[(wr * 64 + mi * 16 + lr) * 32 + lk * 8];
#pragma unroll
        for (int ni = 0; ni < 4; ++ni)
            bfr[ni] = *(const bf16x8*)&Bl[(wc * 64 + ni * 16 + lr) * 32 + lk * 8];
#pragma unroll
        for (int mi = 0; mi < 4; ++mi)
#pragma unroll
            for (int ni = 0; ni < 4; ++ni)
                acc[mi][ni] = __builtin_amdgcn_mfma_f32_16x16x32_bf16(
                    af[mi], bfr[ni], acc[mi][ni], 0, 0, 0);
    }

    // epilogue: C frag layout col = lane&15, row = (lane>>4)*4 + r
#pragma unroll
    for (int mi = 0; mi < 4; ++mi) {
        int row0 = bm + wr * 64 + mi * 16 + lk * 4;
#pragma unroll
        for (int ni = 0; ni < 4; ++ni) {
            int col = bn + wc * 64 + ni * 16 + lr;
            bool cok = col < Nreal;
            float bv = cok ? bias[col] : 0.f;
            float pv = (prelu && cok) ? prelu[col] : 0.f;
#pragma unroll
            for (int r = 0; r < 4; ++r) {
                float val = acc[mi][ni][r] + bv;
                if (prelu) val = val > 0.f ? val : pv * val;
                if (outF && cok) outF[(size_t)(row0 + r) * Nreal + col] = val;
                if (outB) outB[(size_t)(row0 + r) * Np + col] = cok ? f2bf(val) : 0;
            }
        }
    }
}

// ======================= flash attention (masked, online softmax, f32) ==========
// grid: b * 4 heads * 8 q-tiles (64 rows). block 256 = 64 rows x 4 subs.
#define KT 32
__global__ __launch_bounds__(256) void attn_k(
    const float* __restrict__ Q, const float* __restrict__ K,
    const float* __restrict__ V, const unsigned int* __restrict__ abits,
    ushort_t* __restrict__ ctxb)
{
    int blk = blockIdx.x;
    int qt = blk & 7;
    int h  = (blk >> 3) & 3;
    int b  = blk >> 5;
    int t  = threadIdx.x;
    int qr = t >> 2, sub = t & 3;
    int gq = qt * 64 + qr;

    __shared__ float Kt[KT][128];
    __shared__ float Vt[KT][128];

    const float scale = 0.08944271909999159f;  // 1/sqrt(125)
    const size_t rowQ = ((size_t)b * NNODES + gq) * HSZ + (size_t)h * DHEAD;

    float qreg[32];
#pragma unroll
    for (int i4 = 0; i4 < 8; ++i4) {
        int d = sub * 32 + i4 * 4;
        if (d + 3 < DHEAD) {
            float4 qv = *(const float4*)&Q[rowQ + d];
            qreg[i4 * 4]     = qv.x; qreg[i4 * 4 + 1] = qv.y;
            qreg[i4 * 4 + 2] = qv.z; qreg[i4 * 4 + 3] = qv.w;
        } else {
#pragma unroll
            for (int c = 0; c < 4; ++c)
                qreg[i4 * 4 + c] = (d + c < DHEAD) ? Q[rowQ + d + c] : 0.f;
        }
    }

    float acc[32] = {};
    float m = -3e38f, l = 0.f;
    const unsigned int* abrow = abits + ((size_t)b * NNODES + gq) * 16;

    for (int kt = 0; kt < NNODES / KT; ++kt) {
        __syncthreads();
        {
            const float* kb = K + ((size_t)b * NNODES + kt * KT) * HSZ + h * DHEAD;
            const float* vb = V + ((size_t)b * NNODES + kt * KT) * HSZ + h * DHEAD;
            for (int i = t; i < KT * 32; i += 256) {
                int r = i >> 5, c4 = (i & 31) * 4;
                float4 kv, vv;
                if (c4 + 3 < DHEAD) {
                    kv = *(const float4*)&kb[(size_t)r * HSZ + c4];
                    vv = *(const float4*)&vb[(size_t)r * HSZ + c4];
                } else {
                    float tk[4], tv[4];
#pragma unroll
                    for (int c = 0; c < 4; ++c) {
                        bool ok = (c4 + c < DHEAD);
                        tk[c] = ok ? kb[(size_t)r * HSZ + c4 + c] : 0.f;
                        tv[c] = ok ? vb[(size_t)r * HSZ + c4 + c] : 0.f;
                    }
                    kv = make_float4(tk[0], tk[1], tk[2], tk[3]);
                    vv = make_float4(tv[0], tv[1], tv[2], tv[3]);
                }
                *(float4*)&Kt[r][c4] = kv;
                *(float4*)&Vt[r][c4] = vv;
            }
        }
        __syncthreads();

        unsigned int word = abrow[kt];

        for (int j0 = 0; j0 < KT; j0 += 8) {
            float s[8];
#pragma unroll
            for (int jj = 0; jj < 8; ++jj) {
                int j = j0 + jj;
                float a0 = 0.f;
#pragma unroll
                for (int i4 = 0; i4 < 8; ++i4) {
                    float4 kv = *(const float4*)&Kt[j][sub * 32 + i4 * 4];
                    a0 += qreg[i4 * 4] * kv.x + qreg[i4 * 4 + 1] * kv.y
                        + qreg[i4 * 4 + 2] * kv.z + qreg[i4 * 4 + 3] * kv.w;
                }
                s[jj] = a0;
            }
#pragma unroll
            for (int jj = 0; jj < 8; ++jj) {
                s[jj] += __shfl_xor(s[jj], 1);
                s[jj] += __shfl_xor(s[jj], 2);
            }
            float mnew = m;
#pragma unroll
            for (int jj = 0; jj < 8; ++jj) {
                bool on = (word >> (j0 + jj)) & 1u;
                s[jj] = on ? s[jj] * scale : -1e9f;
                mnew = fmaxf(mnew, s[jj]);
            }
            float f = __expf(m - mnew);
            m = mnew;
            l *= f;
#pragma unroll
            for (int i = 0; i < 32; ++i) acc[i] *= f;
#pragma unroll
            for (int jj = 0; jj < 8; ++jj) {
                float p = __expf(s[jj] - m);
                l += p;
                int j = j0 + jj;
#pragma unroll
                for (int i4 = 0; i4 < 8; ++i4) {
                    float4 vv = *(const float4*)&Vt[j][sub * 32 + i4 * 4];
                    acc[i4 * 4]     += p * vv.x;
                    acc[i4 * 4 + 1] += p * vv.y;
                    acc[i4 * 4 + 2] += p * vv.z;
                    acc[i4 * 4 + 3] += p * vv.w;
                }
            }
        }
    }

    float inv = 1.f / l;
    ushort_t* cb = ctxb + ((size_t)b * NNODES + gq) * KP + h * DHEAD;
#pragma unroll
    for (int i = 0; i < 32; ++i) {
        int d = sub * 32 + i;
        if (d < DHEAD) cb[d] = f2bf(acc[i] * inv);
    }
    if (h == 3 && sub == 3) {
        ushort_t* rowp = ctxb + ((size_t)b * NNODES + gq) * KP;
        for (int j = HSZ; j < KP; ++j) rowp[j] = 0;
    }
}

// ======================= layernorm (residual opt) -> f32 + bf16-padded =========
__global__ __launch_bounds__(256) void ln_k(
    const float* __restrict__ x, const float* __restrict__ res,
    const float* __restrict__ g, const float* __restrict__ bta,
    float* __restrict__ outF, ushort_t* __restrict__ outB)
{
    size_t row = blockIdx.x;
    const float* xr = x + row * HSZ;
    const float* rr = res ? res + row * HSZ : nullptr;
    int t = threadIdx.x;
    float v[2];
    float s = 0.f, s2 = 0.f;
#pragma unroll
    for (int i = 0; i < 2; ++i) {
        int d = t + i * 256;
        float val = 0.f;
        if (d < HSZ) { val = xr[d]; if (rr) val += rr[d]; }
        v[i] = val; s += val; s2 += val * val;
    }
    __shared__ float red[8];
    int wave = t >> 6, lane = t & 63;
    for (int o = 1; o < 64; o <<= 1) { s += __shfl_xor(s, o); s2 += __shfl_xor(s2, o); }
    if (lane == 0) { red[wave] = s; red[4 + wave] = s2; }
    __syncthreads();
    s  = red[0] + red[1] + red[2] + red[3];
    s2 = red[4] + red[5] + red[6] + red[7];
    float mean = s / HSZ;
    float var  = s2 / HSZ - mean * mean;
    float rstd = rsqrtf(var + 1e-5f);
    float* orow = outF + row * HSZ;
    ushort_t* brow = outB + row * KP;
#pragma unroll
    for (int i = 0; i < 2; ++i) {
        int d = t + i * 256;
        if (d < HSZ) {
            float o = (v[i] - mean) * rstd * g[d] + bta[d];
            orow[d] = o;
            brow[d] = f2bf(o);
        } else if (d < KP) {
            brow[d] = 0;
        }
    }
}

// ======================= finalize: glob, node_emb, mask =======================
__global__ __launch_bounds__(256) void finalize_k(
    const float* __restrict__ nodes, const int* __restrict__ entity_num,
    float* __restrict__ out)
{
    int b = blockIdx.x / NNODES;
    int n = blockIdx.x % NNODES;
    int e = entity_num[b];
    int size = e + RRELS;
    const float* src = nodes + ((size_t)b * NNODES + n) * HSZ;
    float* ne = out + (size_t)BB * HSZ + ((size_t)b * NNODES + n) * HSZ;
    bool valid = n < size;
    for (int d = threadIdx.x; d < HSZ; d += 256) ne[d] = valid ? src[d] : 0.f;
    if (n == e) {
        float* gl = out + (size_t)b * HSZ;
        for (int d = threadIdx.x; d < HSZ; d += 256) gl[d] = src[d];
    }
    if (threadIdx.x == 0) {
        out[(size_t)BB * HSZ + (size_t)BB * NNODES * HSZ + (size_t)b * NNODES + n] =
            (n <= size) ? 1.f : 0.f;
    }
}

// ======================= host =======================
extern "C" void kernel_launch(void* const* d_in, const int* in_sizes, int n_in,
                              void* d_out, int out_size, void* d_ws, size_t ws_size,
                              hipStream_t stream)
{
    const float* ent_vec    = (const float*)d_in[0];
    const int*   entity_num = (const int*)d_in[1];
    const int*   rels       = (const int*)d_in[2];
    const int*   adj        = (const int*)d_in[3];
    const float* rel_embed  = (const float*)d_in[4];
    const float* Wq = (const float*)d_in[5],  *bq = (const float*)d_in[6];
    const float* Wk = (const float*)d_in[7],  *bk = (const float*)d_in[8];
    const float* Wv = (const float*)d_in[9],  *bv = (const float*)d_in[10];
    const float* Wo = (const float*)d_in[11], *bo = (const float*)d_in[12];
    const float* W1 = (const float*)d_in[13], *b1 = (const float*)d_in[14];
    const float* W2 = (const float*)d_in[15], *b2 = (const float*)d_in[16];
    const float* ln1g = (const float*)d_in[17], *ln1b = (const float*)d_in[18];
    const float* ln2g = (const float*)d_in[19], *ln2b = (const float*)d_in[20];
    const float* pa = (const float*)d_in[21];

    const int M = BB * NNODES;               // 16384
    const size_t S = (size_t)M * HSZ;        // 8,192,000 floats
    float* Af = (float*)d_ws;                // nodesF
    float* Bf = Af + S;                      // q / o
    float* Cf = Bf + S;                      // k / t
    float* Df = Cf + S;                      // v / f
    ushort_t* b16 = (ushort_t*)(Df + S);
    const size_t SP = (size_t)M * KP;        // 8,388,608
    ushort_t* Xb   = b16;
    ushort_t* ctxb = Xb + SP;
    ushort_t* tb   = ctxb + SP;
    ushort_t* h1b  = tb + SP;                // 8192 * 2048 (FFN chunk)
    ushort_t* wqb  = h1b + (size_t)8192 * HIDP;
    ushort_t* wkb  = wqb + KP * KP;
    ushort_t* wvb  = wkb + KP * KP;
    ushort_t* wob  = wvb + KP * KP;
    ushort_t* w1b  = wob + KP * KP;          // [HIDP][KP]
    ushort_t* w2b  = w1b + (size_t)HIDP * KP;// [KP][HIDP]

    unsigned int* abits = (unsigned int*)d_out;  // overwritten by finalize_k

    build_nodes_k<<<BB * NNODES, 256, 0, stream>>>(ent_vec, entity_num, rels, rel_embed, Af, Xb);
    adj_bits_k<<<(BB * NNODES * NNODES) / 64 / 4, 256, 0, stream>>>(adj, abits);

    for (int l = 0; l < NLAYER; ++l) {
        const float* bq_l = bq + (size_t)l * HSZ;
        const float* bk_l = bk + (size_t)l * HSZ;
        const float* bv_l = bv + (size_t)l * HSZ;
        const float* bo_l = bo + (size_t)l * HSZ;
        const float* b1_l = b1 + (size_t)l * HID;
        const float* b2_l = b2 + (size_t)l * HSZ;
        const float* pa_l = pa + (size_t)l * HID;

        // convert+transpose+pad weights for this layer
        wcvt_k<<<(KP * KP) / 256, 256, 0, stream>>>(Wq + (size_t)l * HSZ * HSZ, wqb, HSZ, HSZ, KP, KP);
        wcvt_k<<<(KP * KP) / 256, 256, 0, stream>>>(Wk + (size_t)l * HSZ * HSZ, wkb, HSZ, HSZ, KP, KP);
        wcvt_k<<<(KP * KP) / 256, 256, 0, stream>>>(Wv + (size_t)l * HSZ * HSZ, wvb, HSZ, HSZ, KP, KP);
        wcvt_k<<<(KP * KP) / 256, 256, 0, stream>>>(Wo + (size_t)l * HSZ * HSZ, wob, HSZ, HSZ, KP, KP);
        wcvt_k<<<(HIDP * KP) / 256, 256, 0, stream>>>(W1 + (size_t)l * HSZ * HID, w1b, HSZ, HID, KP, HIDP);
        wcvt_k<<<(KP * HIDP) / 256, 256, 0, stream>>>(W2 + (size_t)l * HID * HSZ, w2b, HID, HSZ, HIDP, KP);

        dim3 gQ(KP / 128, M / 128);  // (4, 128)
        gemm_mfma_k<<<gQ, 256, 0, stream>>>(Xb, wqb, bq_l, Bf, nullptr, M, KP, KP, HSZ, nullptr);
        gemm_mfma_k<<<gQ, 256, 0, stream>>>(Xb, wkb, bk_l, Cf, nullptr, M, KP, KP, HSZ, nullptr);
        gemm_mfma_k<<<gQ, 256, 0, stream>>>(Xb, wvb, bv_l, Df, nullptr, M, KP, KP, HSZ, nullptr);

        attn_k<<<BB * NHEADS_ * (NNODES / 64), 256, 0, stream>>>(Bf, Cf, Df, abits, ctxb);

        gemm_mfma_k<<<gQ, 256, 0, stream>>>(ctxb, wob, bo_l, Bf, nullptr, M, KP, KP, HSZ, nullptr); // o
        ln_k<<<M, 256, 0, stream>>>(Bf, nullptr, ln1g + (size_t)l * HSZ, ln1b + (size_t)l * HSZ, Cf, tb); // t

        // FFN: 2 chunks of 8192 rows
        for (int c = 0; c < 2; ++c) {
            const ushort_t* tch = tb + (size_t)c * 8192 * KP;
            float* fch = Df + (size_t)c * 8192 * HSZ;
            dim3 g1(HIDP / 128, 8192 / 128);  // (16, 64)
            gemm_mfma_k<<<g1, 256, 0, stream>>>(tch, w1b, b1_l, nullptr, h1b, 8192, HIDP, KP, HID, pa_l);
            dim3 g2(KP / 128, 8192 / 128);    // (4, 64)
            gemm_mfma_k<<<g2, 256, 0, stream>>>(h1b, w2b, b2_l, fch, nullptr, 8192, KP, HIDP, HSZ, nullptr);
        }
        ln_k<<<M, 256, 0, stream>>>(Df, Cf, ln2g + (size_t)l * HSZ, ln2b + (size_t)l * HSZ, Af, Xb);
    }

    finalize_k<<<BB * NNODES, 256, 0, stream>>>(Af, entity_num, (float*)d_out);
}

// Round 4
// 887.533 us; speedup vs baseline: 37.4503x; 2.0344x over previous
//
#include <hip/hip_runtime.h>

#define BB 32
#define MEE 384
#define RRELS 128
#define NNODES 512
#define HSZ 500
#define DHEAD 125
#define NHEADS_ 4
#define HID 2000
#define NLAYER 2

#define KP 512      // padded HSZ
#define HIDP 2048   // padded HID

typedef unsigned short ushort_t;
typedef __attribute__((ext_vector_type(8))) short bf16x8;
typedef __attribute__((ext_vector_type(4))) float f32x4;

static __device__ __forceinline__ unsigned short f2bf(float x) {
    unsigned u = __float_as_uint(x);
    u = u + 0x7fff + ((u >> 16) & 1);   // round-to-nearest-even
    return (unsigned short)(u >> 16);
}

static __device__ __forceinline__ void gload_lds16(const ushort_t* g, ushort_t* l) {
    __builtin_amdgcn_global_load_lds(
        (const __attribute__((address_space(1))) void*)g,
        (__attribute__((address_space(3))) void*)l, 16, 0, 0);
}

// ======================= build nodes (f32 + bf16-padded) =======================
__global__ __launch_bounds__(256) void build_nodes_k(
    const float* __restrict__ ent_vec, const int* __restrict__ entity_num,
    const int* __restrict__ rels, const float* __restrict__ rel_embed,
    float* __restrict__ nodes, ushort_t* __restrict__ xb)
{
    int b = blockIdx.x / NNODES;
    int n = blockIdx.x % NNODES;
    int e = entity_num[b];
    const float* src = nullptr;
    if (n < e)               src = ent_vec + ((size_t)b * MEE + n) * HSZ;
    else if (n < e + RRELS)  src = rel_embed + (size_t)rels[b * RRELS + (n - e)] * HSZ;
    float* dst = nodes + ((size_t)b * NNODES + n) * HSZ;
    ushort_t* xd = xb + ((size_t)b * NNODES + n) * KP;
    for (int d = threadIdx.x; d < KP; d += 256) {
        float v = (src && d < HSZ) ? src[d] : 0.f;
        if (d < HSZ) dst[d] = v;
        xd[d] = (d < HSZ) ? f2bf(v) : 0;
    }
}

// ======================= adjacency -> bitmask =======================
__global__ __launch_bounds__(256) void adj_bits_k(
    const int* __restrict__ adj, unsigned int* __restrict__ bits)
{
    int gw = (blockIdx.x * 256 + threadIdx.x) >> 6;
    int lane = threadIdx.x & 63;
    int v = adj[(size_t)gw * 64 + lane];
    unsigned long long mk = __ballot(v != 0);
    if (lane == 0)  bits[gw * 2]     = (unsigned int)mk;
    if (lane == 32) bits[gw * 2 + 1] = (unsigned int)(mk >> 32);
}

// ======================= weight convert: W[K][N] f32 -> Wt[Np][Kp] bf16 =========
__global__ __launch_bounds__(256) void wcvt_k(
    const float* __restrict__ W, ushort_t* __restrict__ out,
    int Kreal, int Nreal, int Kp, int Np)
{
    int idx = blockIdx.x * 256 + threadIdx.x;
    if (idx >= Kp * Np) return;
    int n = idx / Kp, k = idx - n * Kp;
    float v = (k < Kreal && n < Nreal) ? W[(size_t)k * Nreal + n] : 0.f;
    out[idx] = (k < Kreal && n < Nreal) ? f2bf(v) : 0;
}

// ======================= bf16 MFMA GEMM (128x128, BK=32) ========================
// A: [M, Kp] bf16. Bt: [Np, Kp] bf16 (W^T). head_mode: outB is [B][4][512][128].
__global__ __launch_bounds__(256, 2) void gemm_mfma_k(
    const ushort_t* __restrict__ A, const ushort_t* __restrict__ Bt,
    const float* __restrict__ bias,
    float* __restrict__ outF, ushort_t* __restrict__ outB,
    int M, int Np, int Kp, int Nreal,
    const float* __restrict__ prelu, int head_mode)
{
    __shared__ ushort_t Al[128 * 32];
    __shared__ ushort_t Bl[128 * 32];
    const int bm = blockIdx.y * 128;
    const int bn = blockIdx.x * 128;
    const int tid = threadIdx.x;
    const int wid = tid >> 6, lane = tid & 63;
    const int wr = wid >> 1, wc = wid & 1;
    const int lr = lane & 15, lk = lane >> 4;

    f32x4 acc[4][4];
#pragma unroll
    for (int i = 0; i < 4; ++i)
#pragma unroll
        for (int j = 0; j < 4; ++j)
#pragma unroll
            for (int r = 0; r < 4; ++r) acc[i][j][r] = 0.f;

    const int srow = tid >> 2;
    const int skseg = (tid & 3) * 8;
    const ushort_t* Ag0 = A + (size_t)(bm + srow) * Kp + skseg;
    const ushort_t* Ag1 = A + (size_t)(bm + 64 + srow) * Kp + skseg;
    const ushort_t* Bg0 = Bt + (size_t)(bn + srow) * Kp + skseg;
    const ushort_t* Bg1 = Bt + (size_t)(bn + 64 + srow) * Kp + skseg;
    ushort_t* Al0 = &Al[wid * 512];
    ushort_t* Al1 = &Al[2048 + wid * 512];
    ushort_t* Bl0 = &Bl[wid * 512];
    ushort_t* Bl1 = &Bl[2048 + wid * 512];

    for (int k0 = 0; k0 < Kp; k0 += 32) {
        __syncthreads();
        gload_lds16(Ag0 + k0, Al0);
        gload_lds16(Ag1 + k0, Al1);
        gload_lds16(Bg0 + k0, Bl0);
        gload_lds16(Bg1 + k0, Bl1);
        __syncthreads();

        bf16x8 af[4], bfr[4];
#pragma unroll
        for (int mi = 0; mi < 4; ++mi)
            af[mi] = *(const bf16x8*)&Al[(wr * 64 + mi * 16 + lr) * 32 + lk * 8];
#pragma unroll
        for (int ni = 0; ni < 4; ++ni)
            bfr[ni] = *(const bf16x8*)&Bl[(wc * 64 + ni * 16 + lr) * 32 + lk * 8];
#pragma unroll
        for (int mi = 0; mi < 4; ++mi)
#pragma unroll
            for (int ni = 0; ni < 4; ++ni)
                acc[mi][ni] = __builtin_amdgcn_mfma_f32_16x16x32_bf16(
                    af[mi], bfr[ni], acc[mi][ni], 0, 0, 0);
    }

#pragma unroll
    for (int ni = 0; ni < 4; ++ni) {
        int col = bn + wc * 64 + ni * 16 + lr;
        bool cok = col < Nreal;
        float bv = cok ? bias[col] : 0.f;
        float pv = (prelu && cok) ? prelu[col] : 0.f;
        // head decomposition (only used when head_mode)
        int hh, dh;
        if (col < 500) { hh = col / 125; dh = col - hh * 125; }
        else           { hh = (col - 500) / 3; dh = 125 + (col - 500) % 3; }
#pragma unroll
        for (int mi = 0; mi < 4; ++mi) {
            int row0 = bm + wr * 64 + mi * 16 + lk * 4;
#pragma unroll
            for (int r = 0; r < 4; ++r) {
                int row = row0 + r;
                float val = acc[mi][ni][r] + bv;
                if (prelu) val = val > 0.f ? val : pv * val;
                if (!cok) val = 0.f;
                if (head_mode) {
                    size_t idx = (((size_t)(row >> 9) * 4 + hh) * 512 + (row & 511)) * 128 + dh;
                    outB[idx] = f2bf(val);
                } else {
                    if (outF && cok) outF[(size_t)row * Nreal + col] = val;
                    if (outB) outB[(size_t)row * Np + col] = cok ? f2bf(val) : 0;
                }
            }
        }
    }
}

// ======================= V head-layout transpose: vh[bh][512][128] -> vT[bh][128][512]
__global__ __launch_bounds__(256) void vt_k(
    const ushort_t* __restrict__ vh, ushort_t* __restrict__ vT)
{
    int blk = blockIdx.x;
    int dt = blk & 1;          // d-tile (64)
    int nt = (blk >> 1) & 7;   // n-tile (64)
    int bh = blk >> 4;
    int tid = threadIdx.x;
    __shared__ ushort_t T[64 * 64];    // XOR-swizzled by (row&7)

#pragma unroll
    for (int i = 0; i < 2; ++i) {
        int c = tid * 2 + i;           // 0..511 chunks of 8
        int row = c >> 3, c8 = c & 7;
        bf16x8 v = *(const bf16x8*)&vh[((size_t)bh * 512 + nt * 64 + row) * 128 + dt * 64 + c8 * 8];
        *(bf16x8*)&T[row * 64 + ((c8 ^ (row & 7)) << 3)] = v;
    }
    __syncthreads();
#pragma unroll
    for (int i = 0; i < 2; ++i) {
        int c = tid * 2 + i;
        int drow = c >> 3, n8 = (c & 7) * 8;
        bf16x8 o;
#pragma unroll
        for (int j = 0; j < 8; ++j) {
            int n = n8 + j;
            o[j] = (short)T[n * 64 + ((((drow >> 3) ^ (n & 7)) << 3)) + (drow & 7)];
        }
        *(bf16x8*)&vT[((size_t)bh * 128 + dt * 64 + drow) * 512 + nt * 64 + n8] = o;
    }
}

// ======================= MFMA flash attention =======================
// block = (b, h, 64 q-rows); 4 waves x 16 rows; KV tiles of 64 keys.
#define KTT 64
__global__ __launch_bounds__(256, 4) void attn_mfma_k(
    const ushort_t* __restrict__ qh, const ushort_t* __restrict__ kh,
    const ushort_t* __restrict__ vT, const unsigned int* __restrict__ abits,
    ushort_t* __restrict__ ctxb)
{
    __shared__ ushort_t Kl[KTT * 128];       // [key][128d], chunk-swizzled, 16KB
    __shared__ ushort_t Vl[128 * KTT];       // [d][64key],  chunk-swizzled, 16KB
    __shared__ ushort_t Pl[4][16 * KTT];     // per-wave [16q][64key], swizzled, 8KB

    const int blk = blockIdx.x;
    const int qt = blk & 7, h = (blk >> 3) & 3, b = blk >> 5;
    const int tid = threadIdx.x, wid = tid >> 6, lane = tid & 63;
    const int lr = lane & 15, lk = lane >> 4;
    const int bh = b * 4 + h;
    const int q0 = qt * 64 + wid * 16;       // wave's first q row (within batch)
    const float scale = 0.08944271909999159f;

    // Q A-fragments (held in registers for all tiles)
    bf16x8 qa[4];
    {
        const ushort_t* qbase = qh + ((size_t)bh * 512 + q0 + lr) * 128;
#pragma unroll
        for (int ks = 0; ks < 4; ++ks)
            qa[ks] = *(const bf16x8*)&qbase[ks * 32 + lk * 8];
    }

    f32x4 accO[8];
#pragma unroll
    for (int i = 0; i < 8; ++i)
#pragma unroll
        for (int r = 0; r < 4; ++r) accO[i][r] = 0.f;
    float m_[4], l_[4];
#pragma unroll
    for (int r = 0; r < 4; ++r) { m_[r] = -3e38f; l_[r] = 0.f; }

    const unsigned int* ab = abits + ((size_t)b * NNODES + qt * 64 + wid * 16 + lk * 4) * 16;

    for (int kt = 0; kt < NNODES / KTT; ++kt) {
        __syncthreads();
        // stage K tile: 16 chunks-of-1KB, 4 per wave; source pre-swizzled
#pragma unroll
        for (int i = 0; i < 4; ++i) {
            int linear = (wid * 4 + i) * 64 + lane;
            int row = linear >> 4, c = linear & 15;
            int cs = c ^ (row & 7);
            gload_lds16(kh + ((size_t)bh * 512 + kt * 64 + row) * 128 + cs * 8,
                        &Kl[(wid * 4 + i) * 512]);
        }
        // stage V^T tile
#pragma unroll
        for (int i = 0; i < 4; ++i) {
            int linear = (wid * 4 + i) * 64 + lane;
            int row = linear >> 3, c = linear & 7;
            int cs = c ^ (row & 7);
            gload_lds16(vT + ((size_t)bh * 128 + row) * 512 + kt * 64 + cs * 8,
                        &Vl[(wid * 4 + i) * 512]);
        }
        // mask words (2 per row per tile)
        unsigned int mw[4][2];
#pragma unroll
        for (int r = 0; r < 4; ++r) {
            mw[r][0] = ab[r * 16 + kt * 2];
            mw[r][1] = ab[r * 16 + kt * 2 + 1];
        }
        __syncthreads();

        // ---- S = Q K^T (16 q x 64 keys per wave) ----
        f32x4 accS[4];
#pragma unroll
        for (int ni = 0; ni < 4; ++ni)
#pragma unroll
            for (int r = 0; r < 4; ++r) accS[ni][r] = 0.f;
#pragma unroll
        for (int ks = 0; ks < 4; ++ks) {
#pragma unroll
            for (int ni = 0; ni < 4; ++ni) {
                int row = ni * 16 + lr;
                int ch = (ks * 4 + lk) ^ (row & 7);
                bf16x8 kb = *(const bf16x8*)&Kl[row * 128 + ch * 8];
                accS[ni] = __builtin_amdgcn_mfma_f32_16x16x32_bf16(qa[ks], kb, accS[ni], 0, 0, 0);
            }
        }

        // ---- masked online softmax (per r; rows spread over 16-lane groups) ----
#pragma unroll
        for (int r = 0; r < 4; ++r) {
            float s[4];
#pragma unroll
            for (int ni = 0; ni < 4; ++ni) {
                unsigned int word = mw[r][ni >> 1];
                int bit = (ni & 1) * 16 + lr;
                bool on = (word >> bit) & 1u;
                s[ni] = on ? accS[ni][r] * scale : -1e9f;
            }
            float rowmax = fmaxf(fmaxf(s[0], s[1]), fmaxf(s[2], s[3]));
            rowmax = fmaxf(rowmax, __shfl_xor(rowmax, 1));
            rowmax = fmaxf(rowmax, __shfl_xor(rowmax, 2));
            rowmax = fmaxf(rowmax, __shfl_xor(rowmax, 4));
            rowmax = fmaxf(rowmax, __shfl_xor(rowmax, 8));
            float mnew = fmaxf(m_[r], rowmax);
            float f = __expf(m_[r] - mnew);
            m_[r] = mnew;
            float p[4], rs = 0.f;
#pragma unroll
            for (int ni = 0; ni < 4; ++ni) { p[ni] = __expf(s[ni] - mnew); rs += p[ni]; }
            rs += __shfl_xor(rs, 1);
            rs += __shfl_xor(rs, 2);
            rs += __shfl_xor(rs, 4);
            rs += __shfl_xor(rs, 8);
            l_[r] = l_[r] * f + rs;
#pragma unroll
            for (int di = 0; di < 8; ++di) accO[di][r] *= f;
            int q = lk * 4 + r;
#pragma unroll
            for (int ni = 0; ni < 4; ++ni) {
                int key = ni * 16 + lr;
                Pl[wid][q * 64 + (((key >> 3) ^ (q & 7)) << 3) + (key & 7)] = f2bf(p[ni]);
            }
        }

        // ---- O += P V ----
#pragma unroll
        for (int ksp = 0; ksp < 2; ++ksp) {
            int q = lr;
            int k0p = ksp * 32 + lk * 8;
            bf16x8 pa = *(const bf16x8*)&Pl[wid][q * 64 + (((k0p >> 3) ^ (q & 7)) << 3)];
#pragma unroll
            for (int di = 0; di < 8; ++di) {
                int row = di * 16 + lr;
                int ch = (ksp * 4 + lk) ^ (row & 7);
                bf16x8 vb = *(const bf16x8*)&Vl[row * 64 + ch * 8];
                accO[di] = __builtin_amdgcn_mfma_f32_16x16x32_bf16(pa, vb, accO[di], 0, 0, 0);
            }
        }
    }

    // ---- epilogue: O /= l, write bf16 ctx (padded KP) ----
    float inv[4];
#pragma unroll
    for (int r = 0; r < 4; ++r) inv[r] = 1.f / l_[r];
#pragma unroll
    for (int di = 0; di < 8; ++di) {
        int d = di * 16 + lr;
        if (d < DHEAD) {
#pragma unroll
            for (int r = 0; r < 4; ++r) {
                int qg = q0 + lk * 4 + r;
                ctxb[((size_t)b * NNODES + qg) * KP + h * DHEAD + d] = f2bf(accO[di][r] * inv[r]);
            }
        }
    }
    if (h == 3) {  // zero pad cols 500..511 for this block's 64 rows
        int row = q0 + lr;
#pragma unroll
        for (int j = 0; j < 3; ++j)
            ctxb[((size_t)b * NNODES + row) * KP + 500 + lk * 3 + j] = 0;
    }
}

// ======================= layernorm (residual opt) -> f32 + bf16-padded =========
__global__ __launch_bounds__(256) void ln_k(
    const float* __restrict__ x, const float* __restrict__ res,
    const float* __restrict__ g, const float* __restrict__ bta,
    float* __restrict__ outF, ushort_t* __restrict__ outB)
{
    size_t row = blockIdx.x;
    const float* xr = x + row * HSZ;
    const float* rr = res ? res + row * HSZ : nullptr;
    int t = threadIdx.x;
    float v[2];
    float s = 0.f, s2 = 0.f;
#pragma unroll
    for (int i = 0; i < 2; ++i) {
        int d = t + i * 256;
        float val = 0.f;
        if (d < HSZ) { val = xr[d]; if (rr) val += rr[d]; }
        v[i] = val; s += val; s2 += val * val;
    }
    __shared__ float red[8];
    int wave = t >> 6, lane = t & 63;
    for (int o = 1; o < 64; o <<= 1) { s += __shfl_xor(s, o); s2 += __shfl_xor(s2, o); }
    if (lane == 0) { red[wave] = s; red[4 + wave] = s2; }
    __syncthreads();
    s  = red[0] + red[1] + red[2] + red[3];
    s2 = red[4] + red[5] + red[6] + red[7];
    float mean = s / HSZ;
    float var  = s2 / HSZ - mean * mean;
    float rstd = rsqrtf(var + 1e-5f);
    float* orow = outF + row * HSZ;
    ushort_t* brow = outB + row * KP;
#pragma unroll
    for (int i = 0; i < 2; ++i) {
        int d = t + i * 256;
        if (d < HSZ) {
            float o = (v[i] - mean) * rstd * g[d] + bta[d];
            orow[d] = o;
            brow[d] = f2bf(o);
        } else if (d < KP) {
            brow[d] = 0;
        }
    }
}

// ======================= finalize: glob, node_emb, mask =======================
__global__ __launch_bounds__(256) void finalize_k(
    const float* __restrict__ nodes, const int* __restrict__ entity_num,
    float* __restrict__ out)
{
    int b = blockIdx.x / NNODES;
    int n = blockIdx.x % NNODES;
    int e = entity_num[b];
    int size = e + RRELS;
    const float* src = nodes + ((size_t)b * NNODES + n) * HSZ;
    float* ne = out + (size_t)BB * HSZ + ((size_t)b * NNODES + n) * HSZ;
    bool valid = n < size;
    for (int d = threadIdx.x; d < HSZ; d += 256) ne[d] = valid ? src[d] : 0.f;
    if (n == e) {
        float* gl = out + (size_t)b * HSZ;
        for (int d = threadIdx.x; d < HSZ; d += 256) gl[d] = src[d];
    }
    if (threadIdx.x == 0) {
        out[(size_t)BB * HSZ + (size_t)BB * NNODES * HSZ + (size_t)b * NNODES + n] =
            (n <= size) ? 1.f : 0.f;
    }
}

// ======================= host =======================
extern "C" void kernel_launch(void* const* d_in, const int* in_sizes, int n_in,
                              void* d_out, int out_size, void* d_ws, size_t ws_size,
                              hipStream_t stream)
{
    const float* ent_vec    = (const float*)d_in[0];
    const int*   entity_num = (const int*)d_in[1];
    const int*   rels       = (const int*)d_in[2];
    const int*   adj        = (const int*)d_in[3];
    const float* rel_embed  = (const float*)d_in[4];
    const float* Wq = (const float*)d_in[5],  *bq = (const float*)d_in[6];
    const float* Wk = (const float*)d_in[7],  *bk = (const float*)d_in[8];
    const float* Wv = (const float*)d_in[9],  *bv = (const float*)d_in[10];
    const float* Wo = (const float*)d_in[11], *bo = (const float*)d_in[12];
    const float* W1 = (const float*)d_in[13], *b1 = (const float*)d_in[14];
    const float* W2 = (const float*)d_in[15], *b2 = (const float*)d_in[16];
    const float* ln1g = (const float*)d_in[17], *ln1b = (const float*)d_in[18];
    const float* ln2g = (const float*)d_in[19], *ln2b = (const float*)d_in[20];
    const float* pa = (const float*)d_in[21];

    const int M = BB * NNODES;               // 16384
    const size_t S = (size_t)M * HSZ;        // 8,192,000 floats
    float* Af = (float*)d_ws;                // nodesF
    float* Bf = Af + S;                      // o f32 (also vh/vT scratch during attn)
    float* Cf = Bf + S;                      // t f32
    float* Df = Cf + S;                      // f f32
    ushort_t* b16 = (ushort_t*)(Df + S);
    const size_t SP = (size_t)M * KP;        // 8,388,608
    ushort_t* Xb   = b16;
    ushort_t* ctxb = Xb + SP;
    ushort_t* tb   = ctxb + SP;
    ushort_t* h1b  = tb + SP;                // 8192*2048 bf16 = also qh+kh scratch
    ushort_t* wqb  = h1b + (size_t)8192 * HIDP;
    ushort_t* wkb  = wqb + KP * KP;
    ushort_t* wvb  = wkb + KP * KP;
    ushort_t* wob  = wvb + KP * KP;
    ushort_t* w1b  = wob + KP * KP;          // [HIDP][KP]
    ushort_t* w2b  = w1b + (size_t)HIDP * KP;// [KP][HIDP]

    const size_t HBUF = (size_t)BB * NHEADS_ * NNODES * 128;  // 8,388,608
    ushort_t* qh = h1b;                       // dead outside attn phase
    ushort_t* kh = h1b + HBUF;
    ushort_t* vh = (ushort_t*)Bf;             // Bf dead during attn phase
    ushort_t* vTb = vh + HBUF;                // spills 0.78MB into Cf head (dead then)

    unsigned int* abits = (unsigned int*)d_out;  // overwritten by finalize_k

    build_nodes_k<<<BB * NNODES, 256, 0, stream>>>(ent_vec, entity_num, rels, rel_embed, Af, Xb);
    adj_bits_k<<<(BB * NNODES * NNODES) / 64 / 4, 256, 0, stream>>>(adj, abits);

    for (int l = 0; l < NLAYER; ++l) {
        const float* bq_l = bq + (size_t)l * HSZ;
        const float* bk_l = bk + (size_t)l * HSZ;
        const float* bv_l = bv + (size_t)l * HSZ;
        const float* bo_l = bo + (size_t)l * HSZ;
        const float* b1_l = b1 + (size_t)l * HID;
        const float* b2_l = b2 + (size_t)l * HSZ;
        const float* pa_l = pa + (size_t)l * HID;

        wcvt_k<<<(KP * KP) / 256, 256, 0, stream>>>(Wq + (size_t)l * HSZ * HSZ, wqb, HSZ, HSZ, KP, KP);
        wcvt_k<<<(KP * KP) / 256, 256, 0, stream>>>(Wk + (size_t)l * HSZ * HSZ, wkb, HSZ, HSZ, KP, KP);
        wcvt_k<<<(KP * KP) / 256, 256, 0, stream>>>(Wv + (size_t)l * HSZ * HSZ, wvb, HSZ, HSZ, KP, KP);
        wcvt_k<<<(KP * KP) / 256, 256, 0, stream>>>(Wo + (size_t)l * HSZ * HSZ, wob, HSZ, HSZ, KP, KP);
        wcvt_k<<<(HIDP * KP) / 256, 256, 0, stream>>>(W1 + (size_t)l * HSZ * HID, w1b, HSZ, HID, KP, HIDP);
        wcvt_k<<<(KP * HIDP) / 256, 256, 0, stream>>>(W2 + (size_t)l * HID * HSZ, w2b, HID, HSZ, HIDP, KP);

        dim3 gQ(KP / 128, M / 128);  // (4, 128)
        gemm_mfma_k<<<gQ, 256, 0, stream>>>(Xb, wqb, bq_l, nullptr, qh, M, KP, KP, HSZ, nullptr, 1);
        gemm_mfma_k<<<gQ, 256, 0, stream>>>(Xb, wkb, bk_l, nullptr, kh, M, KP, KP, HSZ, nullptr, 1);
        gemm_mfma_k<<<gQ, 256, 0, stream>>>(Xb, wvb, bv_l, nullptr, vh, M, KP, KP, HSZ, nullptr, 1);

        vt_k<<<BB * NHEADS_ * 16, 256, 0, stream>>>(vh, vTb);
        attn_mfma_k<<<BB * NHEADS_ * 8, 256, 0, stream>>>(qh, kh, vTb, abits, ctxb);

        gemm_mfma_k<<<gQ, 256, 0, stream>>>(ctxb, wob, bo_l, Bf, nullptr, M, KP, KP, HSZ, nullptr, 0);
        ln_k<<<M, 256, 0, stream>>>(Bf, nullptr, ln1g + (size_t)l * HSZ, ln1b + (size_t)l * HSZ, Cf, tb);

        for (int c = 0; c < 2; ++c) {
            const ushort_t* tch = tb + (size_t)c * 8192 * KP;
            float* fch = Df + (size_t)c * 8192 * HSZ;
            dim3 g1(HIDP / 128, 8192 / 128);
            gemm_mfma_k<<<g1, 256, 0, stream>>>(tch, w1b, b1_l, nullptr, h1b, 8192, HIDP, KP, HID, pa_l, 0);
            dim3 g2(KP / 128, 8192 / 128);
            gemm_mfma_k<<<g2, 256, 0, stream>>>(h1b, w2b, b2_l, fch, nullptr, 8192, KP, HIDP, HSZ, nullptr, 0);
        }
        ln_k<<<M, 256, 0, stream>>>(Df, Cf, ln2g + (size_t)l * HSZ, ln2b + (size_t)l * HSZ, Af, Xb);
    }

    finalize_k<<<BB * NNODES, 256, 0, stream>>>(Af, entity_num, (float*)d_out);
}

// Round 5
// 728.744 us; speedup vs baseline: 45.6105x; 1.2179x over previous
//
#include <hip/hip_runtime.h>

#define BB 32
#define MEE 384
#define RRELS 128
#define NNODES 512
#define HSZ 500
#define DHEAD 125
#define NHEADS_ 4
#define HID 2000
#define NLAYER 2

#define KP 512      // padded HSZ
#define HIDP 2048   // padded HID

typedef unsigned short ushort_t;
typedef __attribute__((ext_vector_type(8))) short bf16x8;
typedef __attribute__((ext_vector_type(4))) float f32x4;
typedef __attribute__((ext_vector_type(4))) short s16x4;

static __device__ __forceinline__ unsigned short f2bf(float x) {
    unsigned u = __float_as_uint(x);
    u = u + 0x7fff + ((u >> 16) & 1);   // round-to-nearest-even
    return (unsigned short)(u >> 16);
}

static __device__ __forceinline__ void gload_lds16(const ushort_t* g, ushort_t* l) {
    __builtin_amdgcn_global_load_lds(
        (const __attribute__((address_space(1))) void*)g,
        (__attribute__((address_space(3))) void*)l, 16, 0, 0);
}

// ======================= build nodes (f32 + bf16-padded) =======================
__global__ __launch_bounds__(256) void build_nodes_k(
    const float* __restrict__ ent_vec, const int* __restrict__ entity_num,
    const int* __restrict__ rels, const float* __restrict__ rel_embed,
    float* __restrict__ nodes, ushort_t* __restrict__ xb)
{
    int b = blockIdx.x / NNODES;
    int n = blockIdx.x % NNODES;
    int e = entity_num[b];
    const float* src = nullptr;
    if (n < e)               src = ent_vec + ((size_t)b * MEE + n) * HSZ;
    else if (n < e + RRELS)  src = rel_embed + (size_t)rels[b * RRELS + (n - e)] * HSZ;
    float* dst = nodes + ((size_t)b * NNODES + n) * HSZ;
    ushort_t* xd = xb + ((size_t)b * NNODES + n) * KP;
    for (int d = threadIdx.x; d < KP; d += 256) {
        float v = (src && d < HSZ) ? src[d] : 0.f;
        if (d < HSZ) dst[d] = v;
        xd[d] = (d < HSZ) ? f2bf(v) : 0;
    }
}

// ======================= adjacency -> bitmask =======================
__global__ __launch_bounds__(256) void adj_bits_k(
    const int* __restrict__ adj, unsigned int* __restrict__ bits)
{
    int gw = (blockIdx.x * 256 + threadIdx.x) >> 6;
    int lane = threadIdx.x & 63;
    int v = adj[(size_t)gw * 64 + lane];
    unsigned long long mk = __ballot(v != 0);
    if (lane == 0)  bits[gw * 2]     = (unsigned int)mk;
    if (lane == 32) bits[gw * 2 + 1] = (unsigned int)(mk >> 32);
}

// ======================= all-weights convert (one launch per layer) ============
// wqkv [3*512][512], wo [512][512], w1 [2048][512], w2 [512][2048]  (all W^T, bf16)
__global__ __launch_bounds__(256) void wcvt_all_k(
    const float* __restrict__ pWq, const float* __restrict__ pWk,
    const float* __restrict__ pWv, const float* __restrict__ pWo,
    const float* __restrict__ pW1, const float* __restrict__ pW2,
    ushort_t* __restrict__ wqkv, ushort_t* __restrict__ wo,
    ushort_t* __restrict__ w1, ushort_t* __restrict__ w2)
{
    int idx = blockIdx.x * 256 + threadIdx.x;
    if (idx < 786432) {
        int sub = idx / 262144, r = idx % 262144;
        int n = r / 512, k = r % 512;
        const float* W = sub == 0 ? pWq : (sub == 1 ? pWk : pWv);
        wqkv[idx] = (k < 500 && n < 500) ? f2bf(W[k * 500 + n]) : 0;
    } else if (idx < 1048576) {
        int r = idx - 786432; int n = r / 512, k = r % 512;
        wo[r] = (k < 500 && n < 500) ? f2bf(pWo[k * 500 + n]) : 0;
    } else if (idx < 2097152) {
        int r = idx - 1048576; int n = r / 512, k = r % 512;
        w1[r] = (k < 500 && n < 2000) ? f2bf(pW1[k * 2000 + n]) : 0;
    } else if (idx < 3145728) {
        int r = idx - 2097152; int n = r / 2048, k = r % 2048;
        w2[r] = (k < 2000 && n < 500) ? f2bf(pW2[k * 500 + n]) : 0;
    }
}

// ======================= bf16 MFMA GEMM (128x128, BK=32) ========================
// A: [M, Kp] bf16. Bt: [Np, Kp] bf16 (W^T).
// mode 0: outF (f32 [M,Nreal]) and/or outB (bf16 [M,Np] zero-padded)
// mode 1: fused QKV, Np=1536: col region 0->outB(qh), 1->outK(kh),
//         2->outV = V transposed [bh][128][512]
__global__ __launch_bounds__(256, 2) void gemm_mfma_k(
    const ushort_t* __restrict__ A, const ushort_t* __restrict__ Bt,
    const float* __restrict__ bias0, const float* __restrict__ bias1,
    const float* __restrict__ bias2,
    float* __restrict__ outF, ushort_t* __restrict__ outB,
    ushort_t* __restrict__ outK, ushort_t* __restrict__ outV,
    int M, int Np, int Kp, int Nreal,
    const float* __restrict__ prelu, int mode)
{
    __shared__ ushort_t Al[128 * 32];
    __shared__ ushort_t Bl[128 * 32];
    const int bm = blockIdx.y * 128;
    const int bn = blockIdx.x * 128;
    const int tid = threadIdx.x;
    const int wid = tid >> 6, lane = tid & 63;
    const int wr = wid >> 1, wc = wid & 1;
    const int lr = lane & 15, lk = lane >> 4;

    f32x4 acc[4][4];
#pragma unroll
    for (int i = 0; i < 4; ++i)
#pragma unroll
        for (int j = 0; j < 4; ++j)
#pragma unroll
            for (int r = 0; r < 4; ++r) acc[i][j][r] = 0.f;

    const int srow = tid >> 2;
    const int skseg = (tid & 3) * 8;
    const ushort_t* Ag0 = A + (size_t)(bm + srow) * Kp + skseg;
    const ushort_t* Ag1 = A + (size_t)(bm + 64 + srow) * Kp + skseg;
    const ushort_t* Bg0 = Bt + (size_t)(bn + srow) * Kp + skseg;
    const ushort_t* Bg1 = Bt + (size_t)(bn + 64 + srow) * Kp + skseg;
    ushort_t* Al0 = &Al[wid * 512];
    ushort_t* Al1 = &Al[2048 + wid * 512];
    ushort_t* Bl0 = &Bl[wid * 512];
    ushort_t* Bl1 = &Bl[2048 + wid * 512];

    for (int k0 = 0; k0 < Kp; k0 += 32) {
        __syncthreads();
        gload_lds16(Ag0 + k0, Al0);
        gload_lds16(Ag1 + k0, Al1);
        gload_lds16(Bg0 + k0, Bl0);
        gload_lds16(Bg1 + k0, Bl1);
        __syncthreads();

        bf16x8 af[4], bfr[4];
#pragma unroll
        for (int mi = 0; mi < 4; ++mi)
            af[mi] = *(const bf16x8*)&Al[(wr * 64 + mi * 16 + lr) * 32 + lk * 8];
#pragma unroll
        for (int ni = 0; ni < 4; ++ni)
            bfr[ni] = *(const bf16x8*)&Bl[(wc * 64 + ni * 16 + lr) * 32 + lk * 8];
        __builtin_amdgcn_s_setprio(1);
#pragma unroll
        for (int mi = 0; mi < 4; ++mi)
#pragma unroll
            for (int ni = 0; ni < 4; ++ni)
                acc[mi][ni] = __builtin_amdgcn_mfma_f32_16x16x32_bf16(
                    af[mi], bfr[ni], acc[mi][ni], 0, 0, 0);
        __builtin_amdgcn_s_setprio(0);
    }

    if (mode == 1) {
#pragma unroll
        for (int ni = 0; ni < 4; ++ni) {
            int col = bn + wc * 64 + ni * 16 + lr;
            int reg = col >> 9, c = col & 511;
            bool cok = c < 500;
            int hh, dh;
            if (cok) { hh = c / 125; dh = c - hh * 125; }
            else     { hh = (c - 500) / 3; dh = 125 + (c - 500) % 3; }
            const float* bp = reg == 0 ? bias0 : (reg == 1 ? bias1 : bias2);
            float bv = cok ? bp[c] : 0.f;
#pragma unroll
            for (int mi = 0; mi < 4; ++mi) {
                int row0 = bm + wr * 64 + mi * 16 + lk * 4;
                int b_ = row0 >> 9, n0 = row0 & 511;
                size_t bh = (size_t)b_ * 4 + hh;
                if (reg == 2) {
                    s16x4 pk;
#pragma unroll
                    for (int r = 0; r < 4; ++r) {
                        float val = acc[mi][ni][r] + bv;
                        pk[r] = cok ? (short)f2bf(val) : (short)0;
                    }
                    *(s16x4*)&outV[(bh * 128 + dh) * 512 + n0] = pk;
                } else {
                    ushort_t* dst = reg == 0 ? outB : outK;
#pragma unroll
                    for (int r = 0; r < 4; ++r) {
                        float val = acc[mi][ni][r] + bv;
                        dst[(bh * 512 + n0 + r) * 128 + dh] = cok ? f2bf(val) : 0;
                    }
                }
            }
        }
    } else {
#pragma unroll
        for (int ni = 0; ni < 4; ++ni) {
            int col = bn + wc * 64 + ni * 16 + lr;
            bool cok = col < Nreal;
            float bv = cok ? bias0[col] : 0.f;
            float pv = (prelu && cok) ? prelu[col] : 0.f;
#pragma unroll
            for (int mi = 0; mi < 4; ++mi) {
                int row0 = bm + wr * 64 + mi * 16 + lk * 4;
#pragma unroll
                for (int r = 0; r < 4; ++r) {
                    int row = row0 + r;
                    float val = acc[mi][ni][r] + bv;
                    if (prelu) val = val > 0.f ? val : pv * val;
                    if (outF && cok) outF[(size_t)row * Nreal + col] = val;
                    if (outB) outB[(size_t)row * Np + col] = cok ? f2bf(val) : 0;
                }
            }
        }
    }
}

// ======================= MFMA flash attention v2 =======================
// block = (b, h, 128 q-rows); 4 waves x 32 rows; KV tiles of 64 keys,
// double-buffered LDS with prefetch; XCD-chunked block swizzle.
#define KTT 64
__global__ __launch_bounds__(256, 2) void attn_mfma_k(
    const ushort_t* __restrict__ qh, const ushort_t* __restrict__ kh,
    const ushort_t* __restrict__ vT, const unsigned int* __restrict__ abits,
    ushort_t* __restrict__ ctxb)
{
    __shared__ ushort_t Kl[2][KTT * 128];    // 2 x 16KB
    __shared__ ushort_t Vl[2][128 * KTT];    // 2 x 16KB
    __shared__ ushort_t Pl[4][32 * KTT];     // 16KB

    const int bid = blockIdx.x;
    const int wg = (bid & 7) * 64 + (bid >> 3);   // 512 wgs: chunked XCD swizzle
    const int qt2 = wg & 3, bh = wg >> 2;
    const int b = bh >> 2, h = bh & 3;
    const int tid = threadIdx.x, wid = tid >> 6, lane = tid & 63;
    const int lr = lane & 15, lk = lane >> 4;
    const int q0 = qt2 * 128 + wid * 32;          // wave's 32 q rows
    const float scale = 0.08944271909999159f;     // 1/sqrt(125)

    // Q fragments for both 16-row tiles
    bf16x8 qa[2][4];
#pragma unroll
    for (int t = 0; t < 2; ++t) {
        const ushort_t* qbase = qh + ((size_t)bh * 512 + q0 + t * 16 + lr) * 128;
#pragma unroll
        for (int ks = 0; ks < 4; ++ks)
            qa[t][ks] = *(const bf16x8*)&qbase[ks * 32 + lk * 8];
    }

    f32x4 accO[2][8];
#pragma unroll
    for (int t = 0; t < 2; ++t)
#pragma unroll
        for (int i = 0; i < 8; ++i)
#pragma unroll
            for (int r = 0; r < 4; ++r) accO[t][i][r] = 0.f;
    float m_[2][4], l_[2][4];
#pragma unroll
    for (int t = 0; t < 2; ++t)
#pragma unroll
        for (int r = 0; r < 4; ++r) { m_[t][r] = -3e38f; l_[t][r] = 0.f; }

    const unsigned int* ab = abits + ((size_t)b * NNODES + q0) * 16;

    auto stage = [&](int bi, int kt) {
#pragma unroll
        for (int i = 0; i < 4; ++i) {
            int linear = (wid * 4 + i) * 64 + lane;
            int row = linear >> 4, cc = linear & 15;
            int cs = cc ^ (row & 7);
            gload_lds16(kh + ((size_t)bh * 512 + kt * 64 + row) * 128 + cs * 8,
                        &Kl[bi][(wid * 4 + i) * 512]);
        }
#pragma unroll
        for (int i = 0; i < 4; ++i) {
            int linear = (wid * 4 + i) * 64 + lane;
            int row = linear >> 3, cc = linear & 7;
            int cs = cc ^ (row & 7);
            gload_lds16(vT + ((size_t)bh * 128 + row) * 512 + kt * 64 + cs * 8,
                        &Vl[bi][(wid * 4 + i) * 512]);
        }
    };

    stage(0, 0);
    __syncthreads();
    int cur = 0;

    for (int kt = 0; kt < NNODES / KTT; ++kt) {
        if (kt < NNODES / KTT - 1) stage(cur ^ 1, kt + 1);  // prefetch under compute

        unsigned int mw[2][4][2];
#pragma unroll
        for (int t = 0; t < 2; ++t)
#pragma unroll
            for (int r = 0; r < 4; ++r) {
                int qrow = t * 16 + lk * 4 + r;
                mw[t][r][0] = ab[qrow * 16 + kt * 2];
                mw[t][r][1] = ab[qrow * 16 + kt * 2 + 1];
            }

        // ---- S = Q K^T + masked online softmax, per 16-row tile ----
#pragma unroll
        for (int t = 0; t < 2; ++t) {
            f32x4 accS[4];
#pragma unroll
            for (int ni = 0; ni < 4; ++ni)
#pragma unroll
                for (int r = 0; r < 4; ++r) accS[ni][r] = 0.f;
            __builtin_amdgcn_s_setprio(1);
#pragma unroll
            for (int ks = 0; ks < 4; ++ks) {
#pragma unroll
                for (int ni = 0; ni < 4; ++ni) {
                    int row = ni * 16 + lr;
                    int ch = (ks * 4 + lk) ^ (row & 7);
                    bf16x8 kb = *(const bf16x8*)&Kl[cur][row * 128 + ch * 8];
                    accS[ni] = __builtin_amdgcn_mfma_f32_16x16x32_bf16(
                        qa[t][ks], kb, accS[ni], 0, 0, 0);
                }
            }
            __builtin_amdgcn_s_setprio(0);
#pragma unroll
            for (int r = 0; r < 4; ++r) {
                float s[4];
#pragma unroll
                for (int ni = 0; ni < 4; ++ni) {
                    unsigned int word = mw[t][r][ni >> 1];
                    int bit = (ni & 1) * 16 + lr;
                    bool on = (word >> bit) & 1u;
                    s[ni] = on ? accS[ni][r] * scale : -1e9f;
                }
                float rowmax = fmaxf(fmaxf(s[0], s[1]), fmaxf(s[2], s[3]));
                rowmax = fmaxf(rowmax, __shfl_xor(rowmax, 1));
                rowmax = fmaxf(rowmax, __shfl_xor(rowmax, 2));
                rowmax = fmaxf(rowmax, __shfl_xor(rowmax, 4));
                rowmax = fmaxf(rowmax, __shfl_xor(rowmax, 8));
                float mnew = fmaxf(m_[t][r], rowmax);
                float f = __expf(m_[t][r] - mnew);
                m_[t][r] = mnew;
                float p[4], rs = 0.f;
#pragma unroll
                for (int ni = 0; ni < 4; ++ni) { p[ni] = __expf(s[ni] - mnew); rs += p[ni]; }
                rs += __shfl_xor(rs, 1);
                rs += __shfl_xor(rs, 2);
                rs += __shfl_xor(rs, 4);
                rs += __shfl_xor(rs, 8);
                l_[t][r] = l_[t][r] * f + rs;
#pragma unroll
                for (int di = 0; di < 8; ++di) accO[t][di][r] *= f;
                int q = t * 16 + lk * 4 + r;
#pragma unroll
                for (int ni = 0; ni < 4; ++ni) {
                    int key = ni * 16 + lr;
                    Pl[wid][q * 64 + (((key >> 3) ^ (q & 7)) << 3) + (key & 7)] = f2bf(p[ni]);
                }
            }
        }

        // ---- O += P V ----
#pragma unroll
        for (int t = 0; t < 2; ++t) {
#pragma unroll
            for (int ksp = 0; ksp < 2; ++ksp) {
                int q = t * 16 + lr;
                int k0p = ksp * 32 + lk * 8;
                bf16x8 pa = *(const bf16x8*)&Pl[wid][q * 64 + (((k0p >> 3) ^ (q & 7)) << 3)];
                __builtin_amdgcn_s_setprio(1);
#pragma unroll
                for (int di = 0; di < 8; ++di) {
                    int row = di * 16 + lr;
                    int ch = (ksp * 4 + lk) ^ (row & 7);
                    bf16x8 vb = *(const bf16x8*)&Vl[cur][row * 64 + ch * 8];
                    accO[t][di] = __builtin_amdgcn_mfma_f32_16x16x32_bf16(
                        pa, vb, accO[t][di], 0, 0, 0);
                }
                __builtin_amdgcn_s_setprio(0);
            }
        }
        __syncthreads();   // drains prefetch loads + releases cur buffer
        cur ^= 1;
    }

    // ---- epilogue ----
    float inv[2][4];
#pragma unroll
    for (int t = 0; t < 2; ++t)
#pragma unroll
        for (int r = 0; r < 4; ++r) inv[t][r] = 1.f / l_[t][r];
#pragma unroll
    for (int t = 0; t < 2; ++t)
#pragma unroll
        for (int di = 0; di < 8; ++di) {
            int d = di * 16 + lr;
            if (d < DHEAD) {
#pragma unroll
                for (int r = 0; r < 4; ++r) {
                    int qg = q0 + t * 16 + lk * 4 + r;
                    ctxb[((size_t)b * NNODES + qg) * KP + h * DHEAD + d] =
                        f2bf(accO[t][di][r] * inv[t][r]);
                }
            }
        }
    if (h == 3) {  // zero pad cols 500..511 for this wave's 32 rows
        int row = q0 + (lane & 31);
        int c0 = 500 + (lane >> 5) * 6;
#pragma unroll
        for (int j = 0; j < 6; ++j)
            ctxb[((size_t)b * NNODES + row) * KP + c0 + j] = 0;
    }
}

// ======================= layernorm (residual opt) -> f32 + bf16-padded =========
__global__ __launch_bounds__(256) void ln_k(
    const float* __restrict__ x, const float* __restrict__ res,
    const float* __restrict__ g, const float* __restrict__ bta,
    float* __restrict__ outF, ushort_t* __restrict__ outB)
{
    size_t row = blockIdx.x;
    const float* xr = x + row * HSZ;
    const float* rr = res ? res + row * HSZ : nullptr;
    int t = threadIdx.x;
    float v[2];
    float s = 0.f, s2 = 0.f;
#pragma unroll
    for (int i = 0; i < 2; ++i) {
        int d = t + i * 256;
        float val = 0.f;
        if (d < HSZ) { val = xr[d]; if (rr) val += rr[d]; }
        v[i] = val; s += val; s2 += val * val;
    }
    __shared__ float red[8];
    int wave = t >> 6, lane = t & 63;
    for (int o = 1; o < 64; o <<= 1) { s += __shfl_xor(s, o); s2 += __shfl_xor(s2, o); }
    if (lane == 0) { red[wave] = s; red[4 + wave] = s2; }
    __syncthreads();
    s  = red[0] + red[1] + red[2] + red[3];
    s2 = red[4] + red[5] + red[6] + red[7];
    float mean = s / HSZ;
    float var  = s2 / HSZ - mean * mean;
    float rstd = rsqrtf(var + 1e-5f);
    float* orow = outF + row * HSZ;
    ushort_t* brow = outB + row * KP;
#pragma unroll
    for (int i = 0; i < 2; ++i) {
        int d = t + i * 256;
        if (d < HSZ) {
            float o = (v[i] - mean) * rstd * g[d] + bta[d];
            orow[d] = o;
            brow[d] = f2bf(o);
        } else if (d < KP) {
            brow[d] = 0;
        }
    }
}

// ======================= finalize: glob, node_emb, mask =======================
__global__ __launch_bounds__(256) void finalize_k(
    const float* __restrict__ nodes, const int* __restrict__ entity_num,
    float* __restrict__ out)
{
    int b = blockIdx.x / NNODES;
    int n = blockIdx.x % NNODES;
    int e = entity_num[b];
    int size = e + RRELS;
    const float* src = nodes + ((size_t)b * NNODES + n) * HSZ;
    float* ne = out + (size_t)BB * HSZ + ((size_t)b * NNODES + n) * HSZ;
    bool valid = n < size;
    for (int d = threadIdx.x; d < HSZ; d += 256) ne[d] = valid ? src[d] : 0.f;
    if (n == e) {
        float* gl = out + (size_t)b * HSZ;
        for (int d = threadIdx.x; d < HSZ; d += 256) gl[d] = src[d];
    }
    if (threadIdx.x == 0) {
        out[(size_t)BB * HSZ + (size_t)BB * NNODES * HSZ + (size_t)b * NNODES + n] =
            (n <= size) ? 1.f : 0.f;
    }
}

// ======================= host =======================
extern "C" void kernel_launch(void* const* d_in, const int* in_sizes, int n_in,
                              void* d_out, int out_size, void* d_ws, size_t ws_size,
                              hipStream_t stream)
{
    const float* ent_vec    = (const float*)d_in[0];
    const int*   entity_num = (const int*)d_in[1];
    const int*   rels       = (const int*)d_in[2];
    const int*   adj        = (const int*)d_in[3];
    const float* rel_embed  = (const float*)d_in[4];
    const float* Wq = (const float*)d_in[5],  *bq = (const float*)d_in[6];
    const float* Wk = (const float*)d_in[7],  *bk = (const float*)d_in[8];
    const float* Wv = (const float*)d_in[9],  *bv = (const float*)d_in[10];
    const float* Wo = (const float*)d_in[11], *bo = (const float*)d_in[12];
    const float* W1 = (const float*)d_in[13], *b1 = (const float*)d_in[14];
    const float* W2 = (const float*)d_in[15], *b2 = (const float*)d_in[16];
    const float* ln1g = (const float*)d_in[17], *ln1b = (const float*)d_in[18];
    const float* ln2g = (const float*)d_in[19], *ln2b = (const float*)d_in[20];
    const float* pa = (const float*)d_in[21];

    const int M = BB * NNODES;               // 16384
    const size_t S = (size_t)M * HSZ;        // 8,192,000 floats
    float* Af = (float*)d_ws;                // nodesF
    float* Bf = Af + S;                      // o f32 / vT scratch during attn
    float* Cf = Bf + S;                      // t f32
    float* Df = Cf + S;                      // f f32
    ushort_t* b16 = (ushort_t*)(Df + S);
    const size_t SP = (size_t)M * KP;        // 8,388,608
    ushort_t* Xb   = b16;
    ushort_t* ctxb = Xb + SP;
    ushort_t* tb   = ctxb + SP;
    ushort_t* h1b  = tb + SP;                // 8192*2048 bf16 = qh+kh scratch
    ushort_t* wqkvb = h1b + (size_t)8192 * HIDP;  // 3*512*512
    ushort_t* wob  = wqkvb + 3 * KP * KP;
    ushort_t* w1b  = wob + KP * KP;          // [HIDP][KP]
    ushort_t* w2b  = w1b + (size_t)HIDP * KP;// [KP][HIDP]

    const size_t HBUF = (size_t)BB * NHEADS_ * NNODES * 128;  // 8,388,608
    ushort_t* qh = h1b;                       // dead outside attn phase
    ushort_t* kh = h1b + HBUF;
    ushort_t* vTb = (ushort_t*)Bf;            // Bf dead during attn phase

    unsigned int* abits = (unsigned int*)d_out;  // overwritten by finalize_k

    build_nodes_k<<<BB * NNODES, 256, 0, stream>>>(ent_vec, entity_num, rels, rel_embed, Af, Xb);
    adj_bits_k<<<(BB * NNODES * NNODES) / 64 / 4, 256, 0, stream>>>(adj, abits);

    for (int l = 0; l < NLAYER; ++l) {
        const float* bq_l = bq + (size_t)l * HSZ;
        const float* bk_l = bk + (size_t)l * HSZ;
        const float* bv_l = bv + (size_t)l * HSZ;
        const float* bo_l = bo + (size_t)l * HSZ;
        const float* b1_l = b1 + (size_t)l * HID;
        const float* b2_l = b2 + (size_t)l * HSZ;
        const float* pa_l = pa + (size_t)l * HID;

        wcvt_all_k<<<12288, 256, 0, stream>>>(
            Wq + (size_t)l * HSZ * HSZ, Wk + (size_t)l * HSZ * HSZ,
            Wv + (size_t)l * HSZ * HSZ, Wo + (size_t)l * HSZ * HSZ,
            W1 + (size_t)l * HSZ * HID, W2 + (size_t)l * HID * HSZ,
            wqkvb, wob, w1b, w2b);

        // fused QKV: N=1536, writes qh, kh, and vT (transposed) directly
        dim3 gQKV(1536 / 128, M / 128);  // (12, 128)
        gemm_mfma_k<<<gQKV, 256, 0, stream>>>(Xb, wqkvb, bq_l, bk_l, bv_l,
                                              nullptr, qh, kh, vTb,
                                              M, 1536, KP, HSZ, nullptr, 1);

        attn_mfma_k<<<BB * NHEADS_ * 4, 256, 0, stream>>>(qh, kh, vTb, abits, ctxb);

        dim3 gO(KP / 128, M / 128);      // (4, 128)
        gemm_mfma_k<<<gO, 256, 0, stream>>>(ctxb, wob, bo_l, nullptr, nullptr,
                                            Bf, nullptr, nullptr, nullptr,
                                            M, KP, KP, HSZ, nullptr, 0);
        ln_k<<<M, 256, 0, stream>>>(Bf, nullptr, ln1g + (size_t)l * HSZ, ln1b + (size_t)l * HSZ, Cf, tb);

        for (int c = 0; c < 2; ++c) {
            const ushort_t* tch = tb + (size_t)c * 8192 * KP;
            float* fch = Df + (size_t)c * 8192 * HSZ;
            dim3 g1(HIDP / 128, 8192 / 128);
            gemm_mfma_k<<<g1, 256, 0, stream>>>(tch, w1b, b1_l, nullptr, nullptr,
                                                nullptr, h1b, nullptr, nullptr,
                                                8192, HIDP, KP, HID, pa_l, 0);
            dim3 g2(KP / 128, 8192 / 128);
            gemm_mfma_k<<<g2, 256, 0, stream>>>(h1b, w2b, b2_l, nullptr, nullptr,
                                                fch, nullptr, nullptr, nullptr,
                                                8192, KP, HIDP, HSZ, nullptr, 0);
        }
        ln_k<<<M, 256, 0, stream>>>(Df, Cf, ln2g + (size_t)l * HSZ, ln2b + (size_t)l * HSZ, Af, Xb);
    }

    finalize_k<<<BB * NNODES, 256, 0, stream>>>(Af, entity_num, (float*)d_out);
}

// Round 6
// 702.359 us; speedup vs baseline: 47.3240x; 1.0376x over previous
//
#include <hip/hip_runtime.h>

#define BB 32
#define MEE 384
#define RRELS 128
#define NNODES 512
#define HSZ 500
#define DHEAD 125
#define NHEADS_ 4
#define HID 2000
#define NLAYER 2

#define KP 512      // padded HSZ
#define HIDP 2048   // padded HID

typedef unsigned short ushort_t;
typedef __attribute__((ext_vector_type(8))) short bf16x8;
typedef __attribute__((ext_vector_type(4))) float f32x4;
typedef __attribute__((ext_vector_type(4))) short s16x4;

static __device__ __forceinline__ unsigned short f2bf(float x) {
    unsigned u = __float_as_uint(x);
    u = u + 0x7fff + ((u >> 16) & 1);   // round-to-nearest-even
    return (unsigned short)(u >> 16);
}

static __device__ __forceinline__ void gload_lds16(const ushort_t* g, ushort_t* l) {
    __builtin_amdgcn_global_load_lds(
        (const __attribute__((address_space(1))) void*)g,
        (__attribute__((address_space(3))) void*)l, 16, 0, 0);
}

// ======================= build nodes (f32 + bf16-padded) =======================
__global__ __launch_bounds__(256) void build_nodes_k(
    const float* __restrict__ ent_vec, const int* __restrict__ entity_num,
    const int* __restrict__ rels, const float* __restrict__ rel_embed,
    float* __restrict__ nodes, ushort_t* __restrict__ xb)
{
    int b = blockIdx.x / NNODES;
    int n = blockIdx.x % NNODES;
    int e = entity_num[b];
    const float* src = nullptr;
    if (n < e)               src = ent_vec + ((size_t)b * MEE + n) * HSZ;
    else if (n < e + RRELS)  src = rel_embed + (size_t)rels[b * RRELS + (n - e)] * HSZ;
    float* dst = nodes + ((size_t)b * NNODES + n) * HSZ;
    ushort_t* xd = xb + ((size_t)b * NNODES + n) * KP;
    for (int d = threadIdx.x; d < KP; d += 256) {
        float v = (src && d < HSZ) ? src[d] : 0.f;
        if (d < HSZ) dst[d] = v;
        xd[d] = (d < HSZ) ? f2bf(v) : 0;
    }
}

// ======================= adjacency -> bitmask =======================
__global__ __launch_bounds__(256) void adj_bits_k(
    const int* __restrict__ adj, unsigned int* __restrict__ bits)
{
    int gw = (blockIdx.x * 256 + threadIdx.x) >> 6;
    int lane = threadIdx.x & 63;
    int v = adj[(size_t)gw * 64 + lane];
    unsigned long long mk = __ballot(v != 0);
    if (lane == 0)  bits[gw * 2]     = (unsigned int)mk;
    if (lane == 32) bits[gw * 2 + 1] = (unsigned int)(mk >> 32);
}

// ======================= all-weights convert (one launch per layer) ============
__global__ __launch_bounds__(256) void wcvt_all_k(
    const float* __restrict__ pWq, const float* __restrict__ pWk,
    const float* __restrict__ pWv, const float* __restrict__ pWo,
    const float* __restrict__ pW1, const float* __restrict__ pW2,
    ushort_t* __restrict__ wqkv, ushort_t* __restrict__ wo,
    ushort_t* __restrict__ w1, ushort_t* __restrict__ w2)
{
    int idx = blockIdx.x * 256 + threadIdx.x;
    if (idx < 786432) {
        int sub = idx / 262144, r = idx % 262144;
        int n = r / 512, k = r % 512;
        const float* W = sub == 0 ? pWq : (sub == 1 ? pWk : pWv);
        wqkv[idx] = (k < 500 && n < 500) ? f2bf(W[k * 500 + n]) : 0;
    } else if (idx < 1048576) {
        int r = idx - 786432; int n = r / 512, k = r % 512;
        wo[r] = (k < 500 && n < 500) ? f2bf(pWo[k * 500 + n]) : 0;
    } else if (idx < 2097152) {
        int r = idx - 1048576; int n = r / 512, k = r % 512;
        w1[r] = (k < 500 && n < 2000) ? f2bf(pW1[k * 2000 + n]) : 0;
    } else if (idx < 3145728) {
        int r = idx - 2097152; int n = r / 2048, k = r % 2048;
        w2[r] = (k < 2000 && n < 500) ? f2bf(pW2[k * 500 + n]) : 0;
    }
}

// ======================= bf16 MFMA GEMM (128x128, BK=32, dbuf + XCD swizzle) ====
// A: [M, Kp] bf16. Bt: [Np, Kp] bf16 (W^T).
// mode 0: outF (f32 [M,Nreal]) and/or outB (bf16 [M,Np] zero-padded)
// mode 1: fused QKV, Np=1536: col region 0->outB(qh), 1->outK(kh),
//         2->outV = V transposed [bh][128][512]
__global__ __launch_bounds__(256, 2) void gemm_mfma_k(
    const ushort_t* __restrict__ A, const ushort_t* __restrict__ Bt,
    const float* __restrict__ bias0, const float* __restrict__ bias1,
    const float* __restrict__ bias2,
    float* __restrict__ outF, ushort_t* __restrict__ outB,
    ushort_t* __restrict__ outK, ushort_t* __restrict__ outV,
    int M, int Np, int Kp, int Nreal,
    const float* __restrict__ prelu, int mode)
{
    __shared__ ushort_t Al[2][128 * 32];
    __shared__ ushort_t Bl[2][128 * 32];

    // bijective XCD-chunked swizzle (all grids have nwg % 8 == 0)
    const int nwg = gridDim.x * gridDim.y;
    const int bid = blockIdx.y * gridDim.x + blockIdx.x;
    const int swz = (bid & 7) * (nwg >> 3) + (bid >> 3);
    const int bm = (swz / gridDim.x) * 128;
    const int bn = (swz % gridDim.x) * 128;

    const int tid = threadIdx.x;
    const int wid = tid >> 6, lane = tid & 63;
    const int wr = wid >> 1, wc = wid & 1;
    const int lr = lane & 15, lk = lane >> 4;

    f32x4 acc[4][4];
#pragma unroll
    for (int i = 0; i < 4; ++i)
#pragma unroll
        for (int j = 0; j < 4; ++j)
#pragma unroll
            for (int r = 0; r < 4; ++r) acc[i][j][r] = 0.f;

    const int srow = tid >> 2;
    const int skseg = (tid & 3) * 8;
    const ushort_t* Ag0 = A + (size_t)(bm + srow) * Kp + skseg;
    const ushort_t* Ag1 = A + (size_t)(bm + 64 + srow) * Kp + skseg;
    const ushort_t* Bg0 = Bt + (size_t)(bn + srow) * Kp + skseg;
    const ushort_t* Bg1 = Bt + (size_t)(bn + 64 + srow) * Kp + skseg;

    auto stage = [&](int bi, int k0) {
        gload_lds16(Ag0 + k0, &Al[bi][wid * 512]);
        gload_lds16(Ag1 + k0, &Al[bi][2048 + wid * 512]);
        gload_lds16(Bg0 + k0, &Bl[bi][wid * 512]);
        gload_lds16(Bg1 + k0, &Bl[bi][2048 + wid * 512]);
    };

    stage(0, 0);
    __syncthreads();
    int cur = 0;

    for (int k0 = 0; k0 < Kp; k0 += 32) {
        if (k0 + 32 < Kp) stage(cur ^ 1, k0 + 32);   // prefetch under compute

        bf16x8 af[4], bfr[4];
#pragma unroll
        for (int mi = 0; mi < 4; ++mi)
            af[mi] = *(const bf16x8*)&Al[cur][(wr * 64 + mi * 16 + lr) * 32 + lk * 8];
#pragma unroll
        for (int ni = 0; ni < 4; ++ni)
            bfr[ni] = *(const bf16x8*)&Bl[cur][(wc * 64 + ni * 16 + lr) * 32 + lk * 8];
        __builtin_amdgcn_s_setprio(1);
#pragma unroll
        for (int mi = 0; mi < 4; ++mi)
#pragma unroll
            for (int ni = 0; ni < 4; ++ni)
                acc[mi][ni] = __builtin_amdgcn_mfma_f32_16x16x32_bf16(
                    af[mi], bfr[ni], acc[mi][ni], 0, 0, 0);
        __builtin_amdgcn_s_setprio(0);

        __syncthreads();   // drains prefetch + releases cur buffer
        cur ^= 1;
    }

    if (mode == 1) {
#pragma unroll
        for (int ni = 0; ni < 4; ++ni) {
            int col = bn + wc * 64 + ni * 16 + lr;
            int reg = col >> 9, c = col & 511;
            bool cok = c < 500;
            int hh, dh;
            if (cok) { hh = c / 125; dh = c - hh * 125; }
            else     { hh = (c - 500) / 3; dh = 125 + (c - 500) % 3; }
            const float* bp = reg == 0 ? bias0 : (reg == 1 ? bias1 : bias2);
            float bv = cok ? bp[c] : 0.f;
#pragma unroll
            for (int mi = 0; mi < 4; ++mi) {
                int row0 = bm + wr * 64 + mi * 16 + lk * 4;
                int b_ = row0 >> 9, n0 = row0 & 511;
                size_t bh = (size_t)b_ * 4 + hh;
                if (reg == 2) {
                    s16x4 pk;
#pragma unroll
                    for (int r = 0; r < 4; ++r) {
                        float val = acc[mi][ni][r] + bv;
                        pk[r] = cok ? (short)f2bf(val) : (short)0;
                    }
                    *(s16x4*)&outV[(bh * 128 + dh) * 512 + n0] = pk;
                } else {
                    ushort_t* dst = reg == 0 ? outB : outK;
#pragma unroll
                    for (int r = 0; r < 4; ++r) {
                        float val = acc[mi][ni][r] + bv;
                        dst[(bh * 512 + n0 + r) * 128 + dh] = cok ? f2bf(val) : 0;
                    }
                }
            }
        }
    } else {
#pragma unroll
        for (int ni = 0; ni < 4; ++ni) {
            int col = bn + wc * 64 + ni * 16 + lr;
            bool cok = col < Nreal;
            float bv = cok ? bias0[col] : 0.f;
            float pv = (prelu && cok) ? prelu[col] : 0.f;
#pragma unroll
            for (int mi = 0; mi < 4; ++mi) {
                int row0 = bm + wr * 64 + mi * 16 + lk * 4;
#pragma unroll
                for (int r = 0; r < 4; ++r) {
                    int row = row0 + r;
                    float val = acc[mi][ni][r] + bv;
                    if (prelu) val = val > 0.f ? val : pv * val;
                    if (outF && cok) outF[(size_t)row * Nreal + col] = val;
                    if (outB) outB[(size_t)row * Np + col] = cok ? f2bf(val) : 0;
                }
            }
        }
    }
}

// ======================= MFMA flash attention v2 =======================
#define KTT 64
__global__ __launch_bounds__(256, 2) void attn_mfma_k(
    const ushort_t* __restrict__ qh, const ushort_t* __restrict__ kh,
    const ushort_t* __restrict__ vT, const unsigned int* __restrict__ abits,
    ushort_t* __restrict__ ctxb)
{
    __shared__ ushort_t Kl[2][KTT * 128];    // 2 x 16KB
    __shared__ ushort_t Vl[2][128 * KTT];    // 2 x 16KB
    __shared__ ushort_t Pl[4][32 * KTT];     // 16KB

    const int bid = blockIdx.x;
    const int wg = (bid & 7) * 64 + (bid >> 3);   // 512 wgs: chunked XCD swizzle
    const int qt2 = wg & 3, bh = wg >> 2;
    const int b = bh >> 2, h = bh & 3;
    const int tid = threadIdx.x, wid = tid >> 6, lane = tid & 63;
    const int lr = lane & 15, lk = lane >> 4;
    const int q0 = qt2 * 128 + wid * 32;          // wave's 32 q rows
    const float scale = 0.08944271909999159f;     // 1/sqrt(125)

    bf16x8 qa[2][4];
#pragma unroll
    for (int t = 0; t < 2; ++t) {
        const ushort_t* qbase = qh + ((size_t)bh * 512 + q0 + t * 16 + lr) * 128;
#pragma unroll
        for (int ks = 0; ks < 4; ++ks)
            qa[t][ks] = *(const bf16x8*)&qbase[ks * 32 + lk * 8];
    }

    f32x4 accO[2][8];
#pragma unroll
    for (int t = 0; t < 2; ++t)
#pragma unroll
        for (int i = 0; i < 8; ++i)
#pragma unroll
            for (int r = 0; r < 4; ++r) accO[t][i][r] = 0.f;
    float m_[2][4], l_[2][4];
#pragma unroll
    for (int t = 0; t < 2; ++t)
#pragma unroll
        for (int r = 0; r < 4; ++r) { m_[t][r] = -3e38f; l_[t][r] = 0.f; }

    const unsigned int* ab = abits + ((size_t)b * NNODES + q0) * 16;

    auto stage = [&](int bi, int kt) {
#pragma unroll
        for (int i = 0; i < 4; ++i) {
            int linear = (wid * 4 + i) * 64 + lane;
            int row = linear >> 4, cc = linear & 15;
            int cs = cc ^ (row & 7);
            gload_lds16(kh + ((size_t)bh * 512 + kt * 64 + row) * 128 + cs * 8,
                        &Kl[bi][(wid * 4 + i) * 512]);
        }
#pragma unroll
        for (int i = 0; i < 4; ++i) {
            int linear = (wid * 4 + i) * 64 + lane;
            int row = linear >> 3, cc = linear & 7;
            int cs = cc ^ (row & 7);
            gload_lds16(vT + ((size_t)bh * 128 + row) * 512 + kt * 64 + cs * 8,
                        &Vl[bi][(wid * 4 + i) * 512]);
        }
    };

    stage(0, 0);
    __syncthreads();
    int cur = 0;

    for (int kt = 0; kt < NNODES / KTT; ++kt) {
        if (kt < NNODES / KTT - 1) stage(cur ^ 1, kt + 1);  // prefetch under compute

        unsigned int mw[2][4][2];
#pragma unroll
        for (int t = 0; t < 2; ++t)
#pragma unroll
            for (int r = 0; r < 4; ++r) {
                int qrow = t * 16 + lk * 4 + r;
                mw[t][r][0] = ab[qrow * 16 + kt * 2];
                mw[t][r][1] = ab[qrow * 16 + kt * 2 + 1];
            }

#pragma unroll
        for (int t = 0; t < 2; ++t) {
            f32x4 accS[4];
#pragma unroll
            for (int ni = 0; ni < 4; ++ni)
#pragma unroll
                for (int r = 0; r < 4; ++r) accS[ni][r] = 0.f;
            __builtin_amdgcn_s_setprio(1);
#pragma unroll
            for (int ks = 0; ks < 4; ++ks) {
#pragma unroll
                for (int ni = 0; ni < 4; ++ni) {
                    int row = ni * 16 + lr;
                    int ch = (ks * 4 + lk) ^ (row & 7);
                    bf16x8 kb = *(const bf16x8*)&Kl[cur][row * 128 + ch * 8];
                    accS[ni] = __builtin_amdgcn_mfma_f32_16x16x32_bf16(
                        qa[t][ks], kb, accS[ni], 0, 0, 0);
                }
            }
            __builtin_amdgcn_s_setprio(0);
#pragma unroll
            for (int r = 0; r < 4; ++r) {
                float s[4];
#pragma unroll
                for (int ni = 0; ni < 4; ++ni) {
                    unsigned int word = mw[t][r][ni >> 1];
                    int bit = (ni & 1) * 16 + lr;
                    bool on = (word >> bit) & 1u;
                    s[ni] = on ? accS[ni][r] * scale : -1e9f;
                }
                float rowmax = fmaxf(fmaxf(s[0], s[1]), fmaxf(s[2], s[3]));
                rowmax = fmaxf(rowmax, __shfl_xor(rowmax, 1));
                rowmax = fmaxf(rowmax, __shfl_xor(rowmax, 2));
                rowmax = fmaxf(rowmax, __shfl_xor(rowmax, 4));
                rowmax = fmaxf(rowmax, __shfl_xor(rowmax, 8));
                float mnew = fmaxf(m_[t][r], rowmax);
                float f = __expf(m_[t][r] - mnew);
                m_[t][r] = mnew;
                float p[4], rs = 0.f;
#pragma unroll
                for (int ni = 0; ni < 4; ++ni) { p[ni] = __expf(s[ni] - mnew); rs += p[ni]; }
                rs += __shfl_xor(rs, 1);
                rs += __shfl_xor(rs, 2);
                rs += __shfl_xor(rs, 4);
                rs += __shfl_xor(rs, 8);
                l_[t][r] = l_[t][r] * f + rs;
#pragma unroll
                for (int di = 0; di < 8; ++di) accO[t][di][r] *= f;
                int q = t * 16 + lk * 4 + r;
#pragma unroll
                for (int ni = 0; ni < 4; ++ni) {
                    int key = ni * 16 + lr;
                    Pl[wid][q * 64 + (((key >> 3) ^ (q & 7)) << 3) + (key & 7)] = f2bf(p[ni]);
                }
            }
        }

#pragma unroll
        for (int t = 0; t < 2; ++t) {
#pragma unroll
            for (int ksp = 0; ksp < 2; ++ksp) {
                int q = t * 16 + lr;
                int k0p = ksp * 32 + lk * 8;
                bf16x8 pa = *(const bf16x8*)&Pl[wid][q * 64 + (((k0p >> 3) ^ (q & 7)) << 3)];
                __builtin_amdgcn_s_setprio(1);
#pragma unroll
                for (int di = 0; di < 8; ++di) {
                    int row = di * 16 + lr;
                    int ch = (ksp * 4 + lk) ^ (row & 7);
                    bf16x8 vb = *(const bf16x8*)&Vl[cur][row * 64 + ch * 8];
                    accO[t][di] = __builtin_amdgcn_mfma_f32_16x16x32_bf16(
                        pa, vb, accO[t][di], 0, 0, 0);
                }
                __builtin_amdgcn_s_setprio(0);
            }
        }
        __syncthreads();
        cur ^= 1;
    }

    float inv[2][4];
#pragma unroll
    for (int t = 0; t < 2; ++t)
#pragma unroll
        for (int r = 0; r < 4; ++r) inv[t][r] = 1.f / l_[t][r];
#pragma unroll
    for (int t = 0; t < 2; ++t)
#pragma unroll
        for (int di = 0; di < 8; ++di) {
            int d = di * 16 + lr;
            if (d < DHEAD) {
#pragma unroll
                for (int r = 0; r < 4; ++r) {
                    int qg = q0 + t * 16 + lk * 4 + r;
                    ctxb[((size_t)b * NNODES + qg) * KP + h * DHEAD + d] =
                        f2bf(accO[t][di][r] * inv[t][r]);
                }
            }
        }
    if (h == 3) {
        int row = q0 + (lane & 31);
        int c0 = 500 + (lane >> 5) * 6;
#pragma unroll
        for (int j = 0; j < 6; ++j)
            ctxb[((size_t)b * NNODES + row) * KP + c0 + j] = 0;
    }
}

// ======================= layernorm (residual opt) -> f32 + bf16-padded =========
__global__ __launch_bounds__(256) void ln_k(
    const float* __restrict__ x, const float* __restrict__ res,
    const float* __restrict__ g, const float* __restrict__ bta,
    float* __restrict__ outF, ushort_t* __restrict__ outB)
{
    size_t row = blockIdx.x;
    const float* xr = x + row * HSZ;
    const float* rr = res ? res + row * HSZ : nullptr;
    int t = threadIdx.x;
    float v[2];
    float s = 0.f, s2 = 0.f;
#pragma unroll
    for (int i = 0; i < 2; ++i) {
        int d = t + i * 256;
        float val = 0.f;
        if (d < HSZ) { val = xr[d]; if (rr) val += rr[d]; }
        v[i] = val; s += val; s2 += val * val;
    }
    __shared__ float red[8];
    int wave = t >> 6, lane = t & 63;
    for (int o = 1; o < 64; o <<= 1) { s += __shfl_xor(s, o); s2 += __shfl_xor(s2, o); }
    if (lane == 0) { red[wave] = s; red[4 + wave] = s2; }
    __syncthreads();
    s  = red[0] + red[1] + red[2] + red[3];
    s2 = red[4] + red[5] + red[6] + red[7];
    float mean = s / HSZ;
    float var  = s2 / HSZ - mean * mean;
    float rstd = rsqrtf(var + 1e-5f);
    float* orow = outF + row * HSZ;
    ushort_t* brow = outB + row * KP;
#pragma unroll
    for (int i = 0; i < 2; ++i) {
        int d = t + i * 256;
        if (d < HSZ) {
            float o = (v[i] - mean) * rstd * g[d] + bta[d];
            orow[d] = o;
            brow[d] = f2bf(o);
        } else if (d < KP) {
            brow[d] = 0;
        }
    }
}

// ======================= finalize: glob, node_emb, mask =======================
__global__ __launch_bounds__(256) void finalize_k(
    const float* __restrict__ nodes, const int* __restrict__ entity_num,
    float* __restrict__ out)
{
    int b = blockIdx.x / NNODES;
    int n = blockIdx.x % NNODES;
    int e = entity_num[b];
    int size = e + RRELS;
    const float* src = nodes + ((size_t)b * NNODES + n) * HSZ;
    float* ne = out + (size_t)BB * HSZ + ((size_t)b * NNODES + n) * HSZ;
    bool valid = n < size;
    for (int d = threadIdx.x; d < HSZ; d += 256) ne[d] = valid ? src[d] : 0.f;
    if (n == e) {
        float* gl = out + (size_t)b * HSZ;
        for (int d = threadIdx.x; d < HSZ; d += 256) gl[d] = src[d];
    }
    if (threadIdx.x == 0) {
        out[(size_t)BB * HSZ + (size_t)BB * NNODES * HSZ + (size_t)b * NNODES + n] =
            (n <= size) ? 1.f : 0.f;
    }
}

// ======================= host =======================
extern "C" void kernel_launch(void* const* d_in, const int* in_sizes, int n_in,
                              void* d_out, int out_size, void* d_ws, size_t ws_size,
                              hipStream_t stream)
{
    const float* ent_vec    = (const float*)d_in[0];
    const int*   entity_num = (const int*)d_in[1];
    const int*   rels       = (const int*)d_in[2];
    const int*   adj        = (const int*)d_in[3];
    const float* rel_embed  = (const float*)d_in[4];
    const float* Wq = (const float*)d_in[5],  *bq = (const float*)d_in[6];
    const float* Wk = (const float*)d_in[7],  *bk = (const float*)d_in[8];
    const float* Wv = (const float*)d_in[9],  *bv = (const float*)d_in[10];
    const float* Wo = (const float*)d_in[11], *bo = (const float*)d_in[12];
    const float* W1 = (const float*)d_in[13], *b1 = (const float*)d_in[14];
    const float* W2 = (const float*)d_in[15], *b2 = (const float*)d_in[16];
    const float* ln1g = (const float*)d_in[17], *ln1b = (const float*)d_in[18];
    const float* ln2g = (const float*)d_in[19], *ln2b = (const float*)d_in[20];
    const float* pa = (const float*)d_in[21];

    const int M = BB * NNODES;               // 16384
    const size_t S = (size_t)M * HSZ;        // 8,192,000 floats
    float* Af = (float*)d_ws;                // nodesF
    float* Bf = Af + S;                      // o f32 / vT scratch during attn
    float* Cf = Bf + S;                      // t f32
    float* Df = Cf + S;                      // f f32
    ushort_t* b16 = (ushort_t*)(Df + S);
    const size_t SP = (size_t)M * KP;        // 8,388,608
    ushort_t* Xb   = b16;
    ushort_t* ctxb = Xb + SP;
    ushort_t* tb   = ctxb + SP;
    ushort_t* h1b  = tb + SP;                // 8192*2048 bf16 = qh+kh scratch
    ushort_t* wqkvb = h1b + (size_t)8192 * HIDP;  // 3*512*512
    ushort_t* wob  = wqkvb + 3 * KP * KP;
    ushort_t* w1b  = wob + KP * KP;          // [HIDP][KP]
    ushort_t* w2b  = w1b + (size_t)HIDP * KP;// [KP][HIDP]

    const size_t HBUF = (size_t)BB * NHEADS_ * NNODES * 128;  // 8,388,608
    ushort_t* qh = h1b;                       // dead outside attn phase
    ushort_t* kh = h1b + HBUF;
    ushort_t* vTb = (ushort_t*)Bf;            // Bf dead during attn phase

    unsigned int* abits = (unsigned int*)d_out;  // overwritten by finalize_k

    build_nodes_k<<<BB * NNODES, 256, 0, stream>>>(ent_vec, entity_num, rels, rel_embed, Af, Xb);
    adj_bits_k<<<(BB * NNODES * NNODES) / 64 / 4, 256, 0, stream>>>(adj, abits);

    for (int l = 0; l < NLAYER; ++l) {
        const float* bq_l = bq + (size_t)l * HSZ;
        const float* bk_l = bk + (size_t)l * HSZ;
        const float* bv_l = bv + (size_t)l * HSZ;
        const float* bo_l = bo + (size_t)l * HSZ;
        const float* b1_l = b1 + (size_t)l * HID;
        const float* b2_l = b2 + (size_t)l * HSZ;
        const float* pa_l = pa + (size_t)l * HID;

        wcvt_all_k<<<12288, 256, 0, stream>>>(
            Wq + (size_t)l * HSZ * HSZ, Wk + (size_t)l * HSZ * HSZ,
            Wv + (size_t)l * HSZ * HSZ, Wo + (size_t)l * HSZ * HSZ,
            W1 + (size_t)l * HSZ * HID, W2 + (size_t)l * HID * HSZ,
            wqkvb, wob, w1b, w2b);

        // fused QKV: N=1536, writes qh, kh, and vT (transposed) directly
        dim3 gQKV(1536 / 128, M / 128);  // (12, 128)
        gemm_mfma_k<<<gQKV, 256, 0, stream>>>(Xb, wqkvb, bq_l, bk_l, bv_l,
                                              nullptr, qh, kh, vTb,
                                              M, 1536, KP, HSZ, nullptr, 1);

        attn_mfma_k<<<BB * NHEADS_ * 4, 256, 0, stream>>>(qh, kh, vTb, abits, ctxb);

        dim3 gO(KP / 128, M / 128);      // (4, 128)
        gemm_mfma_k<<<gO, 256, 0, stream>>>(ctxb, wob, bo_l, nullptr, nullptr,
                                            Bf, nullptr, nullptr, nullptr,
                                            M, KP, KP, HSZ, nullptr, 0);
        ln_k<<<M, 256, 0, stream>>>(Bf, nullptr, ln1g + (size_t)l * HSZ, ln1b + (size_t)l * HSZ, Cf, tb);

        for (int c = 0; c < 2; ++c) {
            const ushort_t* tch = tb + (size_t)c * 8192 * KP;
            float* fch = Df + (size_t)c * 8192 * HSZ;
            dim3 g1(HIDP / 128, 8192 / 128);
            gemm_mfma_k<<<g1, 256, 0, stream>>>(tch, w1b, b1_l, nullptr, nullptr,
                                                nullptr, h1b, nullptr, nullptr,
                                                8192, HIDP, KP, HID, pa_l, 0);
            dim3 g2(KP / 128, 8192 / 128);
            gemm_mfma_k<<<g2, 256, 0, stream>>>(h1b, w2b, b2_l, nullptr, nullptr,
                                                fch, nullptr, nullptr, nullptr,
                                                8192, KP, HIDP, HSZ, nullptr, 0);
        }
        ln_k<<<M, 256, 0, stream>>>(Df, Cf, ln2g + (size_t)l * HSZ, ln2b + (size_t)l * HSZ, Af, Xb);
    }

    finalize_k<<<BB * NNODES, 256, 0, stream>>>(Af, entity_num, (float*)d_out);
}